// Round 16
// baseline (178.548 us; speedup 1.0000x reference)
//
#include <hip/hip_runtime.h>
#include <hip/hip_bf16.h>
#include <hip/hip_fp16.h>
#include <stdint.h>

// Problem constants
#define BATCH 256
#define NPOS 49
#define CCH 128
#define KWIN 7
#define HEADS 4
#define K2 49
#define HD 32
#define MROWS (BATCH * NPOS)         // 12544
#define QSCALE 0.17677669529663687f  // 32^-0.5

using short8 = __attribute__((ext_vector_type(8))) short;
using floatx4 = __attribute__((ext_vector_type(4))) float;

static __device__ inline short f2bf(float x) {
  uint32_t u = __float_as_uint(x);
  uint32_t r = (u + 0x7fffu + ((u >> 16) & 1u)) >> 16;
  return (short)r;
}

// ---------------------------------------------------------------------------
// GEMM 0 (r15): x @ [w_qkv;w_off]^T -> qkv_bf (bf16, q pre-scaled) + off_h.
// ---------------------------------------------------------------------------
__global__ __launch_bounds__(256) void dwa_gemm0(
    const float* __restrict__ x, const float* __restrict__ w_qkv,
    const float* __restrict__ w_off, const float* __restrict__ b_qkv,
    const float* __restrict__ b_off, short* __restrict__ qkv_bf,
    __half* __restrict__ off_h) {
  __shared__ short Abs[64][128];
  __shared__ short Bbs[64][128];
  const int tid = threadIdx.x;
  const int m0 = blockIdx.x * 64;

#pragma unroll
  for (int p = 0; p < 4; ++p) {
    int c = tid + p * 256;
    int row = c >> 4;
    int slot = c & 15;
    const float* src = x + (size_t)(m0 + row) * 128 + slot * 8;
    float4 f0 = *(const float4*)(src);
    float4 f1 = *(const float4*)(src + 4);
    short8 pk;
    pk[0] = f2bf(f0.x); pk[1] = f2bf(f0.y); pk[2] = f2bf(f0.z); pk[3] = f2bf(f0.w);
    pk[4] = f2bf(f1.x); pk[5] = f2bf(f1.y); pk[6] = f2bf(f1.z); pk[7] = f2bf(f1.w);
    *(short8*)&Abs[row][(slot ^ (row & 7)) * 8] = pk;
  }

  const int lane = tid & 63;
  const int wv = tid >> 6;
  const int wrow = (wv >> 1) * 32;
  const int wcol = (wv & 1) * 32;
  const int lr = lane & 15;
  const int lg = lane >> 4;

#pragma unroll
  for (int t = 0; t < 3; ++t) {
    const int ntile = blockIdx.y + 5 * t;
    if (ntile >= 13) break;
    const int n0 = ntile * 64;
#pragma unroll
    for (int p = 0; p < 4; ++p) {
      int c = tid + p * 256;
      int row = c >> 4;
      int slot = c & 15;
      int colg = n0 + row;
      float4 f0 = make_float4(0.f, 0.f, 0.f, 0.f), f1 = f0;
      if (colg < 384) {
        const float* src = w_qkv + (size_t)colg * 128 + slot * 8;
        f0 = *(const float4*)(src);
        f1 = *(const float4*)(src + 4);
      } else if (colg < 776) {
        const float* src = w_off + (size_t)(colg - 384) * 128 + slot * 8;
        f0 = *(const float4*)(src);
        f1 = *(const float4*)(src + 4);
      }
      short8 pk;
      pk[0] = f2bf(f0.x); pk[1] = f2bf(f0.y); pk[2] = f2bf(f0.z); pk[3] = f2bf(f0.w);
      pk[4] = f2bf(f1.x); pk[5] = f2bf(f1.y); pk[6] = f2bf(f1.z); pk[7] = f2bf(f1.w);
      *(short8*)&Bbs[row][(slot ^ (row & 7)) * 8] = pk;
    }
    __syncthreads();

    floatx4 acc[2][2];
#pragma unroll
    for (int i = 0; i < 2; ++i)
#pragma unroll
      for (int j = 0; j < 2; ++j) acc[i][j] = {0.f, 0.f, 0.f, 0.f};
#pragma unroll
    for (int ks = 0; ks < 4; ++ks) {
      short8 af[2], bf[2];
#pragma unroll
      for (int i = 0; i < 2; ++i) {
        int r = wrow + i * 16 + lr;
        int slot = (ks * 4 + lg) ^ (r & 7);
        af[i] = *(const short8*)&Abs[r][slot * 8];
      }
#pragma unroll
      for (int j = 0; j < 2; ++j) {
        int r = wcol + j * 16 + lr;
        int slot = (ks * 4 + lg) ^ (r & 7);
        bf[j] = *(const short8*)&Bbs[r][slot * 8];
      }
#pragma unroll
      for (int i = 0; i < 2; ++i)
#pragma unroll
        for (int j = 0; j < 2; ++j)
          acc[i][j] = __builtin_amdgcn_mfma_f32_16x16x32_bf16(af[i], bf[j],
                                                              acc[i][j], 0, 0, 0);
    }
#pragma unroll
    for (int i = 0; i < 2; ++i) {
#pragma unroll
      for (int reg = 0; reg < 4; ++reg) {
        int grow = m0 + wrow + i * 16 + lg * 4 + reg;
#pragma unroll
        for (int j = 0; j < 2; ++j) {
          int gcol = n0 + wcol + j * 16 + lr;
          float v = acc[i][j][reg];
          if (gcol < 384) {
            float sc = (gcol < 128) ? QSCALE : 1.0f;
            qkv_bf[(size_t)grow * 384 + gcol] = f2bf((v + b_qkv[gcol]) * sc);
          } else if (gcol < 776) {
            off_h[(size_t)grow * 392 + (gcol - 384)] =
                __float2half(v + b_off[gcol - 384]);
          }
        }
      }
    }
    __syncthreads();
  }
}

// ---------------------------------------------------------------------------
// ABLATION template of r15's attn kernel. PH: 0=skeleton(barriers only),
// 1=+stage, 2=+S0 MFMA, 5=+scatter with PLAIN (racy) LDS adds,
// 3=+scatter with atomicAdd, 4=FULL (real outputs). Identical grid/LDS/
// launch_bounds across variants; non-4 variants keep values alive via
// asm volatile (rule: ablation-via-skip DCEs upstream ops otherwise).
// ---------------------------------------------------------------------------
template <int PH>
__global__ __launch_bounds__(256, 8) void dwa_attn_t(
    const short* __restrict__ qkv_bf, const __half* __restrict__ off_h,
    const float* __restrict__ rpb, float* __restrict__ attn_out,
    float* __restrict__ rs_buf) {
  __shared__ __align__(16) short region1[3840];  // qbs(1280)+kbs(2560) / A2b
  __shared__ __align__(16) __half S0h[1356];     // [26][52] fp16 + pad
  __shared__ __align__(16) short vbT[32 * 72];   // bf16 v^T [d][m]
  __shared__ __align__(16) float A2f[1354];      // [26][52] f32 + pad

  short* qbs = region1;
  short* kbs = region1 + 1280;
  short* A2b = region1;

  const int bid = blockIdx.x;
  const int swz = (bid & 7) * 256 + (bid >> 3);
  const int b = swz >> 3;
  const int sub = swz & 7;
  const int h = sub >> 1;
  const int half = sub & 1;
  const int bn0 = half * 25;
  const int rcnt = half ? 24 : 25;
  const int nslots = rcnt * 49;

  const int tid = threadIdx.x;
  const int lane = tid & 63;
  const int wv = tid >> 6;
  const int lr = lane & 15;
  const int lg = lane >> 4;

  float probe = 0.f;
  float2 offr[5];
  float biasr[5];
#pragma unroll
  for (int p = 0; p < 5; ++p) { offr[p] = make_float2(0.f, 0.f); biasr[p] = 0.f; }

  if constexpr (PH >= 1) {
    // ---- prefetch offsets (fp16) + bias to regs ----
    const __half* offp = off_h + (size_t)(b * 49) * 392 + h * 98;
#pragma unroll
    for (int p = 0; p < 5; ++p) {
      int e = tid + p * 256;
      if (e < nslots) {
        unsigned nu = (unsigned)e / 49u;
        int k2 = e - (int)nu * 49;
        unsigned ku = (unsigned)k2;
        int ky = (int)(ku / 7u), kx = k2 - ky * 7;
        __half2 o2 =
            *(const __half2*)(offp + (size_t)(bn0 + (int)nu) * 392 + k2 * 2);
        offr[p] = __half22float2(o2);
        biasr[p] = rpb[h * 169 + (ky + 3) * 13 + (kx + 3)];
      }
    }
    // ---- P1 stage ----
    short8 zz = {0, 0, 0, 0, 0, 0, 0, 0};
    {
      int r = tid >> 2, c4 = tid & 3;
      short8 pk = zz;
      if (r < 49)
        pk = *(const short8*)(qkv_bf + (size_t)(b * 49 + r) * 384 + 128 +
                              h * 32 + c4 * 8);
      *(short8*)&kbs[r * 40 + c4 * 8] = pk;
    }
    if (tid < 128) {
      int r = tid >> 2, c4 = tid & 3;
      short8 pk = zz;
      if (r < rcnt)
        pk = *(const short8*)(qkv_bf + (size_t)(b * 49 + bn0 + r) * 384 +
                              h * 32 + c4 * 8);
      *(short8*)&qbs[r * 40 + c4 * 8] = pk;
    }
    const short* vbase = qkv_bf + (size_t)(b * 49) * 384 + 256 + h * 32;
#pragma unroll
    for (int it = 0; it < 7; ++it) {
      int i = tid + it * 256;
      if (i < 1568) {
        int n = i >> 5;
        int d = i & 31;
        vbT[d * 72 + n] = vbase[(size_t)n * 384 + d];
      }
    }
    for (int i = tid; i < 480; i += 256) {
      int d = i / 15;
      int j = i - d * 15;
      vbT[d * 72 + 49 + j] = 0;
    }
    float4 z4 = make_float4(0.f, 0.f, 0.f, 0.f);
    for (int i = tid; i < 338; i += 256) *(float4*)&A2f[i * 4] = z4;
    if (tid < 2) A2f[1352 + tid] = 0.f;
    if (tid < 16) S0h[25 * 52 + tid] = __float2half(0.f);
  }
  __syncthreads();  // B1 (all variants)

  if constexpr (PH >= 2) {
    // ---- P2: S0h = k@q^T via MFMA ----
    const int mt = wv;
    short8 af = *(const short8*)&kbs[(mt * 16 + lr) * 40 + lg * 8];
    floatx4 z = {0.f, 0.f, 0.f, 0.f};
#pragma unroll
    for (int nt = 0; nt < 2; ++nt) {
      short8 bf = *(const short8*)&qbs[(nt * 16 + lr) * 40 + lg * 8];
      floatx4 c = __builtin_amdgcn_mfma_f32_16x16x32_bf16(af, bf, z, 0, 0, 0);
      int n = nt * 16 + lr;
      int mbase = mt * 16 + lg * 4;
      if (n < 26 && mbase < 52) {
        short4 pk;
        pk.x = (short)__half_as_ushort(__float2half(c[0]));
        pk.y = (short)__half_as_ushort(__float2half(c[1]));
        pk.z = (short)__half_as_ushort(__float2half(c[2]));
        pk.w = (short)__half_as_ushort(__float2half(c[3]));
        *(short4*)&S0h[n * 52 + mbase] = pk;
      }
    }
  }
  __syncthreads();  // B2 (all variants)

  if constexpr (PH == 3 || PH == 4 || PH == 5) {
    // ---- P3: scores + exp + scatter (atomic unless PH==5) ----
#pragma unroll
    for (int p = 0; p < 5; ++p) {
      int e = tid + p * 256;
      if (e < nslots) {
        unsigned nu = (unsigned)e / 49u;
        int n = (int)nu;
        int k2 = e - n * 49;
        int gn = bn0 + n;
        unsigned gnu = (unsigned)gn;
        int iy = (int)(gnu / 7u), ix = gn - iy * 7;
        unsigned ku = (unsigned)k2;
        int ky = (int)(ku / 7u), kx = k2 - ky * 7;
        float py = fminf(fmaxf((float)(iy + ky - 3) + offr[p].x, 0.f), 6.f);
        float px = fminf(fmaxf((float)(ix + kx - 3) + offr[p].y, 0.f), 6.f);
        float y0f = floorf(py), x0f = floorf(px);
        float wy = py - y0f, wx = px - x0f;
        int base = n * 52 + (int)y0f * 7 + (int)x0f;
        float s00 = __half2float(S0h[base]);
        float s01 = __half2float(S0h[base + 1]);
        float s10 = __half2float(S0h[base + 7]);
        float s11 = __half2float(S0h[base + 8]);
        float w00 = (1.f - wy) * (1.f - wx);
        float w01 = (1.f - wy) * wx;
        float w10 = wy * (1.f - wx);
        float w11 = wy * wx;
        float s = w00 * s00 + w01 * s01 + w10 * s10 + w11 * s11 + biasr[p];
        float pe = __expf(s);
        if constexpr (PH == 5) {  // plain racy adds: isolates atomic premium
          A2f[base] += pe * w00;
          A2f[base + 1] += pe * w01;
          A2f[base + 7] += pe * w10;
          A2f[base + 8] += pe * w11;
        } else {
          atomicAdd(&A2f[base], pe * w00);
          atomicAdd(&A2f[base + 1], pe * w01);
          atomicAdd(&A2f[base + 7], pe * w10);
          atomicAdd(&A2f[base + 8], pe * w11);
        }
      }
    }
  }
  __syncthreads();  // B3 (all variants)

  if constexpr (PH == 4) {
    // ---- P4: A2f -> A2b bf16 ----
    if (tid < 208) {
      int n = tid >> 3;
      int j8 = tid & 7;
      short8 pk = {0, 0, 0, 0, 0, 0, 0, 0};
      if (j8 < 6) {
        const float* src = &A2f[n * 52 + j8 * 8];
        float4 f0 = *(const float4*)(src);
        float4 f1 = *(const float4*)(src + 4);
        pk[0] = f2bf(f0.x); pk[1] = f2bf(f0.y); pk[2] = f2bf(f0.z); pk[3] = f2bf(f0.w);
        pk[4] = f2bf(f1.x); pk[5] = f2bf(f1.y); pk[6] = f2bf(f1.z); pk[7] = f2bf(f1.w);
      } else if (j8 == 6) {
        pk[0] = f2bf(A2f[n * 52 + 48]);
      }
      *(short8*)&A2b[n * 72 + j8 * 8] = pk;
    }
  }
  __syncthreads();  // B4 (all variants)

  if constexpr (PH == 4) {
    // ---- P5: out + rowsum via MFMA (real outputs) ----
    const int nt = wv & 1;
    const int dt = wv >> 1;
    floatx4 acc = {0.f, 0.f, 0.f, 0.f};
    floatx4 accS = {0.f, 0.f, 0.f, 0.f};
    short8 bones;
#pragma unroll
    for (int u = 0; u < 8; ++u) bones[u] = (lr == 0) ? (short)0x3F80 : (short)0;
#pragma unroll
    for (int ks = 0; ks < 2; ++ks) {
      short8 af = *(const short8*)&A2b[(nt * 16 + lr) * 72 + ks * 32 + lg * 8];
      short8 bf = *(const short8*)&vbT[(dt * 16 + lr) * 72 + ks * 32 + lg * 8];
      acc = __builtin_amdgcn_mfma_f32_16x16x32_bf16(af, bf, acc, 0, 0, 0);
      if (dt == 0)
        accS = __builtin_amdgcn_mfma_f32_16x16x32_bf16(af, bones, accS, 0, 0, 0);
    }
    const int d = dt * 16 + lr;
#pragma unroll
    for (int reg = 0; reg < 4; ++reg) {
      int n = nt * 16 + lg * 4 + reg;
      if (n < rcnt) {
        int grow = b * 49 + bn0 + n;
        attn_out[(size_t)grow * 128 + h * 32 + d] = acc[reg];
        if (dt == 0 && lr == 0) rs_buf[(size_t)grow * 4 + h] = accS[reg];
      }
    }
  } else {
    // keep-alive: reference every LDS array + all reg state (no DCE)
    probe += (float)region1[(tid * 7) & 3839];
    probe += __half2float(S0h[tid & 1351]);
    probe += (float)vbT[(tid * 5) & 2303];
    probe += A2f[tid & 1351];
#pragma unroll
    for (int p = 0; p < 5; ++p) probe += offr[p].x + offr[p].y + biasr[p];
    asm volatile("" ::"v"(probe));
  }
}

// ---------------------------------------------------------------------------
// Proj GEMM (r15): out = diag(1/rs per head) * attn_out @ w_proj^T + b_proj
// ---------------------------------------------------------------------------
__global__ __launch_bounds__(256) void dwa_proj(
    const float* __restrict__ A, const float* __restrict__ W0,
    const float* __restrict__ bias0, float* __restrict__ out0,
    const float* __restrict__ rs) {
  __shared__ short Abs[64][128];
  __shared__ short Bbs[64][128];
  const int tid = threadIdx.x;
  const int m0 = blockIdx.x * 64;
  const int n0 = blockIdx.y * 64;

#pragma unroll
  for (int p = 0; p < 4; ++p) {
    int c = tid + p * 256;
    int row = c >> 4;
    int slot = c & 15;
    const float* src = A + (size_t)(m0 + row) * 128 + slot * 8;
    float4 f0 = *(const float4*)(src);
    float4 f1 = *(const float4*)(src + 4);
    float irs = 1.0f / rs[(size_t)(m0 + row) * 4 + (slot >> 2)];
    f0.x *= irs; f0.y *= irs; f0.z *= irs; f0.w *= irs;
    f1.x *= irs; f1.y *= irs; f1.z *= irs; f1.w *= irs;
    short8 pk;
    pk[0] = f2bf(f0.x); pk[1] = f2bf(f0.y); pk[2] = f2bf(f0.z); pk[3] = f2bf(f0.w);
    pk[4] = f2bf(f1.x); pk[5] = f2bf(f1.y); pk[6] = f2bf(f1.z); pk[7] = f2bf(f1.w);
    *(short8*)&Abs[row][(slot ^ (row & 7)) * 8] = pk;
  }
#pragma unroll
  for (int p = 0; p < 4; ++p) {
    int c = tid + p * 256;
    int row = c >> 4;
    int slot = c & 15;
    const float* src = W0 + (size_t)(n0 + row) * 128 + slot * 8;
    float4 f0 = *(const float4*)(src);
    float4 f1 = *(const float4*)(src + 4);
    short8 pk;
    pk[0] = f2bf(f0.x); pk[1] = f2bf(f0.y); pk[2] = f2bf(f0.z); pk[3] = f2bf(f0.w);
    pk[4] = f2bf(f1.x); pk[5] = f2bf(f1.y); pk[6] = f2bf(f1.z); pk[7] = f2bf(f1.w);
    *(short8*)&Bbs[row][(slot ^ (row & 7)) * 8] = pk;
  }
  __syncthreads();

  const int lane = tid & 63;
  const int wv = tid >> 6;
  const int wrow = (wv >> 1) * 32;
  const int wcol = (wv & 1) * 32;
  const int lr = lane & 15;
  const int lg = lane >> 4;

  floatx4 acc[2][2];
#pragma unroll
  for (int i = 0; i < 2; ++i)
#pragma unroll
    for (int j = 0; j < 2; ++j) acc[i][j] = {0.f, 0.f, 0.f, 0.f};

#pragma unroll
  for (int ks = 0; ks < 4; ++ks) {
    short8 af[2], bf[2];
#pragma unroll
    for (int i = 0; i < 2; ++i) {
      int r = wrow + i * 16 + lr;
      int slot = (ks * 4 + lg) ^ (r & 7);
      af[i] = *(const short8*)&Abs[r][slot * 8];
    }
#pragma unroll
    for (int j = 0; j < 2; ++j) {
      int r = wcol + j * 16 + lr;
      int slot = (ks * 4 + lg) ^ (r & 7);
      bf[j] = *(const short8*)&Bbs[r][slot * 8];
    }
#pragma unroll
    for (int i = 0; i < 2; ++i)
#pragma unroll
      for (int j = 0; j < 2; ++j)
        acc[i][j] = __builtin_amdgcn_mfma_f32_16x16x32_bf16(af[i], bf[j],
                                                            acc[i][j], 0, 0, 0);
  }

#pragma unroll
  for (int i = 0; i < 2; ++i) {
#pragma unroll
    for (int reg = 0; reg < 4; ++reg) {
      int grow = m0 + wrow + i * 16 + lg * 4 + reg;
#pragma unroll
      for (int j = 0; j < 2; ++j) {
        int gcol = n0 + wcol + j * 16 + lr;
        out0[(size_t)grow * 128 + gcol] = acc[i][j][reg] + bias0[gcol];
      }
    }
  }
}

// ---------------------------------------------------------------------------
extern "C" void kernel_launch(void* const* d_in, const int* in_sizes, int n_in,
                              void* d_out, int out_size, void* d_ws,
                              size_t ws_size, hipStream_t stream) {
  const float* x = (const float*)d_in[0];
  const float* w_qkv = (const float*)d_in[1];
  const float* b_qkv = (const float*)d_in[2];
  const float* w_off = (const float*)d_in[3];
  const float* b_off = (const float*)d_in[4];
  const float* rpb = (const float*)d_in[5];
  const float* w_proj = (const float*)d_in[6];
  const float* b_proj = (const float*)d_in[7];
  float* out = (float*)d_out;

  char* ws = (char*)d_ws;
  short* qkv_bf = (short*)ws;                              // 12544*384*2B
  __half* off_h = (__half*)(ws + (size_t)MROWS * 384 * 2); // 12544*392*2B
  float* attn_out = (float*)(ws + (size_t)MROWS * 384 * 2 +
                             (size_t)MROWS * 392 * 2);     // 12544*128*4B
  float* rs_buf = attn_out + (size_t)MROWS * 128;          // 12544*4

  dwa_gemm0<<<dim3(196, 5), 256, 0, stream>>>(x, w_qkv, w_off, b_qkv, b_off,
                                              qkv_bf, off_h);
  // ---- ablation ladder (diagnostic; non-4 variants write nothing) ----
  dwa_attn_t<0><<<2048, 256, 0, stream>>>(qkv_bf, off_h, rpb, attn_out, rs_buf);
  dwa_attn_t<1><<<2048, 256, 0, stream>>>(qkv_bf, off_h, rpb, attn_out, rs_buf);
  dwa_attn_t<2><<<2048, 256, 0, stream>>>(qkv_bf, off_h, rpb, attn_out, rs_buf);
  dwa_attn_t<5><<<2048, 256, 0, stream>>>(qkv_bf, off_h, rpb, attn_out, rs_buf);
  dwa_attn_t<3><<<2048, 256, 0, stream>>>(qkv_bf, off_h, rpb, attn_out, rs_buf);
  // ---- real attention ----
  dwa_attn_t<4><<<2048, 256, 0, stream>>>(qkv_bf, off_h, rpb, attn_out, rs_buf);
  dwa_proj<<<dim3(196, 2), 256, 0, stream>>>(attn_out, w_proj, b_proj, out,
                                             rs_buf);
}

// Round 17
// 91.563 us; speedup vs baseline: 1.9500x; 1.9500x over previous
//
#include <hip/hip_runtime.h>
#include <hip/hip_bf16.h>
#include <hip/hip_fp16.h>
#include <stdint.h>

// Problem constants
#define BATCH 256
#define NPOS 49
#define CCH 128
#define KWIN 7
#define HEADS 4
#define K2 49
#define HD 32
#define MROWS (BATCH * NPOS)         // 12544
#define QSCALE 0.17677669529663687f  // 32^-0.5

using short8 = __attribute__((ext_vector_type(8))) short;
using floatx4 = __attribute__((ext_vector_type(4))) float;

static __device__ inline short f2bf(float x) {
  uint32_t u = __float_as_uint(x);
  uint32_t r = (u + 0x7fffu + ((u >> 16) & 1u)) >> 16;
  return (short)r;
}

// ---------------------------------------------------------------------------
// GEMM 0 (r15): x @ [w_qkv;w_off]^T -> qkv_bf (bf16, q pre-scaled) + off_h.
// ---------------------------------------------------------------------------
__global__ __launch_bounds__(256) void dwa_gemm0(
    const float* __restrict__ x, const float* __restrict__ w_qkv,
    const float* __restrict__ w_off, const float* __restrict__ b_qkv,
    const float* __restrict__ b_off, short* __restrict__ qkv_bf,
    __half* __restrict__ off_h) {
  __shared__ short Abs[64][128];
  __shared__ short Bbs[64][128];
  const int tid = threadIdx.x;
  const int m0 = blockIdx.x * 64;

#pragma unroll
  for (int p = 0; p < 4; ++p) {
    int c = tid + p * 256;
    int row = c >> 4;
    int slot = c & 15;
    const float* src = x + (size_t)(m0 + row) * 128 + slot * 8;
    float4 f0 = *(const float4*)(src);
    float4 f1 = *(const float4*)(src + 4);
    short8 pk;
    pk[0] = f2bf(f0.x); pk[1] = f2bf(f0.y); pk[2] = f2bf(f0.z); pk[3] = f2bf(f0.w);
    pk[4] = f2bf(f1.x); pk[5] = f2bf(f1.y); pk[6] = f2bf(f1.z); pk[7] = f2bf(f1.w);
    *(short8*)&Abs[row][(slot ^ (row & 7)) * 8] = pk;
  }

  const int lane = tid & 63;
  const int wv = tid >> 6;
  const int wrow = (wv >> 1) * 32;
  const int wcol = (wv & 1) * 32;
  const int lr = lane & 15;
  const int lg = lane >> 4;

#pragma unroll
  for (int t = 0; t < 3; ++t) {
    const int ntile = blockIdx.y + 5 * t;
    if (ntile >= 13) break;
    const int n0 = ntile * 64;
#pragma unroll
    for (int p = 0; p < 4; ++p) {
      int c = tid + p * 256;
      int row = c >> 4;
      int slot = c & 15;
      int colg = n0 + row;
      float4 f0 = make_float4(0.f, 0.f, 0.f, 0.f), f1 = f0;
      if (colg < 384) {
        const float* src = w_qkv + (size_t)colg * 128 + slot * 8;
        f0 = *(const float4*)(src);
        f1 = *(const float4*)(src + 4);
      } else if (colg < 776) {
        const float* src = w_off + (size_t)(colg - 384) * 128 + slot * 8;
        f0 = *(const float4*)(src);
        f1 = *(const float4*)(src + 4);
      }
      short8 pk;
      pk[0] = f2bf(f0.x); pk[1] = f2bf(f0.y); pk[2] = f2bf(f0.z); pk[3] = f2bf(f0.w);
      pk[4] = f2bf(f1.x); pk[5] = f2bf(f1.y); pk[6] = f2bf(f1.z); pk[7] = f2bf(f1.w);
      *(short8*)&Bbs[row][(slot ^ (row & 7)) * 8] = pk;
    }
    __syncthreads();

    floatx4 acc[2][2];
#pragma unroll
    for (int i = 0; i < 2; ++i)
#pragma unroll
      for (int j = 0; j < 2; ++j) acc[i][j] = {0.f, 0.f, 0.f, 0.f};
#pragma unroll
    for (int ks = 0; ks < 4; ++ks) {
      short8 af[2], bf[2];
#pragma unroll
      for (int i = 0; i < 2; ++i) {
        int r = wrow + i * 16 + lr;
        int slot = (ks * 4 + lg) ^ (r & 7);
        af[i] = *(const short8*)&Abs[r][slot * 8];
      }
#pragma unroll
      for (int j = 0; j < 2; ++j) {
        int r = wcol + j * 16 + lr;
        int slot = (ks * 4 + lg) ^ (r & 7);
        bf[j] = *(const short8*)&Bbs[r][slot * 8];
      }
#pragma unroll
      for (int i = 0; i < 2; ++i)
#pragma unroll
        for (int j = 0; j < 2; ++j)
          acc[i][j] = __builtin_amdgcn_mfma_f32_16x16x32_bf16(af[i], bf[j],
                                                              acc[i][j], 0, 0, 0);
    }
#pragma unroll
    for (int i = 0; i < 2; ++i) {
#pragma unroll
      for (int reg = 0; reg < 4; ++reg) {
        int grow = m0 + wrow + i * 16 + lg * 4 + reg;
#pragma unroll
        for (int j = 0; j < 2; ++j) {
          int gcol = n0 + wcol + j * 16 + lr;
          float v = acc[i][j][reg];
          if (gcol < 384) {
            float sc = (gcol < 128) ? QSCALE : 1.0f;
            qkv_bf[(size_t)grow * 384 + gcol] = f2bf((v + b_qkv[gcol]) * sc);
          } else if (gcol < 776) {
            off_h[(size_t)grow * 392 + (gcol - 384)] =
                __float2half(v + b_off[gcol - 384]);
          }
        }
      }
    }
    __syncthreads();
  }
}

// ---------------------------------------------------------------------------
// Deformable window attention (r15 structure) with the r16-ablation fix:
// the LDS atomicAdd scatter was measured to BE the ~60us floor (PH3==PH4
// ~66us while racy PH5 ~5us -> same-address ds_add_f32 serialization from
// border-row clamping). Fix: FOUR lane-interleaved A2 copies (copy = tid&3).
// Stride-7 clamp-collision groups {k2,k2+7,k2+14,k2+21} map to 4 DISTINCT
// copies; corner 16-groups spread 4/copy -> worst same-address 16->4.
// Copy stride 1356 floats (16B-aligned; banks 0/12/24/4 -> parallel).
// P4 sums the 4 copies during bf16 conversion. LDS ~37.5 KB -> 4 blocks/CU.
// ---------------------------------------------------------------------------
__global__ __launch_bounds__(256, 4) void dwa_attn(
    const short* __restrict__ qkv_bf, const __half* __restrict__ off_h,
    const float* __restrict__ rpb, float* __restrict__ attn_out,
    float* __restrict__ rs_buf) {
  __shared__ __align__(16) short region1[3840];  // qbs(1280)+kbs(2560) / A2b
  __shared__ __align__(16) __half S0h[1356];     // [26][52] fp16 + pad
  __shared__ __align__(16) short vbT[32 * 72];   // bf16 v^T [d][m]
  __shared__ __align__(16) float A2f[4 * 1356];  // 4 lane-interleaved copies

  short* qbs = region1;          // [32][40] bf16
  short* kbs = region1 + 1280;   // [64][40] bf16
  short* A2b = region1;          // [32][72] bf16 (aliases qbs/kbs after P2)

  const int bid = blockIdx.x;
  const int swz = (bid & 7) * 256 + (bid >> 3);
  const int b = swz >> 3;
  const int sub = swz & 7;
  const int h = sub >> 1;
  const int half = sub & 1;
  const int bn0 = half * 25;
  const int rcnt = half ? 24 : 25;
  const int nslots = rcnt * 49;

  const int tid = threadIdx.x;
  const int lane = tid & 63;
  const int wv = tid >> 6;
  const int lr = lane & 15;
  const int lg = lane >> 4;
  const int cp = tid & 3;  // A2 copy index (breaks stride-7 collision groups)

  // ---- prefetch offsets (fp16) + bias to regs ----
  const __half* offp = off_h + (size_t)(b * 49) * 392 + h * 98;
  float2 offr[5];
  float biasr[5];
#pragma unroll
  for (int p = 0; p < 5; ++p) {
    int e = tid + p * 256;
    if (e < nslots) {
      unsigned nu = (unsigned)e / 49u;
      int k2 = e - (int)nu * 49;
      unsigned ku = (unsigned)k2;
      int ky = (int)(ku / 7u), kx = k2 - ky * 7;
      __half2 o2 =
          *(const __half2*)(offp + (size_t)(bn0 + (int)nu) * 392 + k2 * 2);
      offr[p] = __half22float2(o2);
      biasr[p] = rpb[h * 169 + (ky + 3) * 13 + (kx + 3)];
    }
  }

  // ---- P1 stage (pure copies) ----
  {
    short8 zz = {0, 0, 0, 0, 0, 0, 0, 0};
    {
      int r = tid >> 2, c4 = tid & 3;
      short8 pk = zz;
      if (r < 49)
        pk = *(const short8*)(qkv_bf + (size_t)(b * 49 + r) * 384 + 128 +
                              h * 32 + c4 * 8);
      *(short8*)&kbs[r * 40 + c4 * 8] = pk;
    }
    if (tid < 128) {
      int r = tid >> 2, c4 = tid & 3;
      short8 pk = zz;
      if (r < rcnt)
        pk = *(const short8*)(qkv_bf + (size_t)(b * 49 + bn0 + r) * 384 +
                              h * 32 + c4 * 8);
      *(short8*)&qbs[r * 40 + c4 * 8] = pk;
    }
    const short* vbase = qkv_bf + (size_t)(b * 49) * 384 + 256 + h * 32;
#pragma unroll
    for (int it = 0; it < 7; ++it) {
      int i = tid + it * 256;
      if (i < 1568) {
        int n = i >> 5;
        int d = i & 31;
        vbT[d * 72 + n] = vbase[(size_t)n * 384 + d];
      }
    }
    for (int i = tid; i < 480; i += 256) {  // zero vbT cols 49..63, all d
      int d = i / 15;
      int j = i - d * 15;
      vbT[d * 72 + 49 + j] = 0;
    }
    // zero all 4 A2 copies: 4*1356 floats = 1356 float4
    float4 z4 = make_float4(0.f, 0.f, 0.f, 0.f);
    for (int i = tid; i < 1356; i += 256) ((float4*)A2f)[i] = z4;
    if (tid < 16) S0h[25 * 52 + tid] = __float2half(0.f);
  }
  __syncthreads();  // B1

  // ---- P2: S0h[n][m] = k_m . q_n via mfma(A=k, B=q); fp16 b64 writes ----
  {
    const int mt = wv;
    short8 af = *(const short8*)&kbs[(mt * 16 + lr) * 40 + lg * 8];
    floatx4 z = {0.f, 0.f, 0.f, 0.f};
#pragma unroll
    for (int nt = 0; nt < 2; ++nt) {
      short8 bf = *(const short8*)&qbs[(nt * 16 + lr) * 40 + lg * 8];
      floatx4 c = __builtin_amdgcn_mfma_f32_16x16x32_bf16(af, bf, z, 0, 0, 0);
      int n = nt * 16 + lr;
      int mbase = mt * 16 + lg * 4;
      if (n < 26 && mbase < 52) {  // both guards required (row pitch 52)
        short4 pk;
        pk.x = (short)__half_as_ushort(__float2half(c[0]));
        pk.y = (short)__half_as_ushort(__float2half(c[1]));
        pk.z = (short)__half_as_ushort(__float2half(c[2]));
        pk.w = (short)__half_as_ushort(__float2half(c[3]));
        *(short4*)&S0h[n * 52 + mbase] = pk;
      }
    }
  }
  __syncthreads();  // B2

  // ---- P3: scores + exp + scatter into per-(tid&3) A2 copy ----
#pragma unroll
  for (int p = 0; p < 5; ++p) {
    int e = tid + p * 256;
    if (e < nslots) {
      unsigned nu = (unsigned)e / 49u;
      int n = (int)nu;
      int k2 = e - n * 49;
      int gn = bn0 + n;
      unsigned gnu = (unsigned)gn;
      int iy = (int)(gnu / 7u), ix = gn - iy * 7;
      unsigned ku = (unsigned)k2;
      int ky = (int)(ku / 7u), kx = k2 - ky * 7;
      float py = fminf(fmaxf((float)(iy + ky - 3) + offr[p].x, 0.f), 6.f);
      float px = fminf(fmaxf((float)(ix + kx - 3) + offr[p].y, 0.f), 6.f);
      float y0f = floorf(py), x0f = floorf(px);
      float wy = py - y0f, wx = px - x0f;
      int base = n * 52 + (int)y0f * 7 + (int)x0f;
      float s00 = __half2float(S0h[base]);
      float s01 = __half2float(S0h[base + 1]);
      float s10 = __half2float(S0h[base + 7]);
      float s11 = __half2float(S0h[base + 8]);
      float w00 = (1.f - wy) * (1.f - wx);
      float w01 = (1.f - wy) * wx;
      float w10 = wy * (1.f - wx);
      float w11 = wy * wx;
      float s = w00 * s00 + w01 * s01 + w10 * s10 + w11 * s11 + biasr[p];
      float pe = __expf(s);
      float* ap = A2f + cp * 1356 + base;
      atomicAdd(ap, pe * w00);
      atomicAdd(ap + 1, pe * w01);
      atomicAdd(ap + 7, pe * w10);
      atomicAdd(ap + 8, pe * w11);
    }
  }
  __syncthreads();  // B3

  // ---- P4: sum 4 copies, A2f -> A2b bf16 [32][72]; cols 48+ masked ----
  if (tid < 208) {
    int n = tid >> 3;
    int j8 = tid & 7;
    short8 pk = {0, 0, 0, 0, 0, 0, 0, 0};
    if (j8 < 6) {
      float4 f0 = make_float4(0.f, 0.f, 0.f, 0.f), f1 = f0;
#pragma unroll
      for (int c = 0; c < 4; ++c) {
        const float* src = A2f + c * 1356 + n * 52 + j8 * 8;
        float4 a0 = *(const float4*)(src);
        float4 a1 = *(const float4*)(src + 4);
        f0.x += a0.x; f0.y += a0.y; f0.z += a0.z; f0.w += a0.w;
        f1.x += a1.x; f1.y += a1.y; f1.z += a1.z; f1.w += a1.w;
      }
      pk[0] = f2bf(f0.x); pk[1] = f2bf(f0.y); pk[2] = f2bf(f0.z); pk[3] = f2bf(f0.w);
      pk[4] = f2bf(f1.x); pk[5] = f2bf(f1.y); pk[6] = f2bf(f1.z); pk[7] = f2bf(f1.w);
    } else if (j8 == 6) {
      float s48 = 0.f;
#pragma unroll
      for (int c = 0; c < 4; ++c) s48 += A2f[c * 1356 + n * 52 + 48];
      pk[0] = f2bf(s48);  // col 48; 49..55 zero
    }  // j8==7: cols 56..63 zero
    *(short8*)&A2b[n * 72 + j8 * 8] = pk;
  }
  __syncthreads();  // B4

  // ---- P5: out + rowsum via MFMA ----
  {
    const int nt = wv & 1;
    const int dt = wv >> 1;
    floatx4 acc = {0.f, 0.f, 0.f, 0.f};
    floatx4 accS = {0.f, 0.f, 0.f, 0.f};
    short8 bones;
#pragma unroll
    for (int u = 0; u < 8; ++u) bones[u] = (lr == 0) ? (short)0x3F80 : (short)0;
#pragma unroll
    for (int ks = 0; ks < 2; ++ks) {
      short8 af = *(const short8*)&A2b[(nt * 16 + lr) * 72 + ks * 32 + lg * 8];
      short8 bf = *(const short8*)&vbT[(dt * 16 + lr) * 72 + ks * 32 + lg * 8];
      acc = __builtin_amdgcn_mfma_f32_16x16x32_bf16(af, bf, acc, 0, 0, 0);
      if (dt == 0)
        accS = __builtin_amdgcn_mfma_f32_16x16x32_bf16(af, bones, accS, 0, 0, 0);
    }
    const int d = dt * 16 + lr;
#pragma unroll
    for (int reg = 0; reg < 4; ++reg) {
      int n = nt * 16 + lg * 4 + reg;
      if (n < rcnt) {
        int grow = b * 49 + bn0 + n;
        attn_out[(size_t)grow * 128 + h * 32 + d] = acc[reg];
        if (dt == 0 && lr == 0) rs_buf[(size_t)grow * 4 + h] = accS[reg];
      }
    }
  }
}

// ---------------------------------------------------------------------------
// Proj GEMM: out = diag(1/rs per head) * attn_out @ w_proj^T + b_proj
// ---------------------------------------------------------------------------
__global__ __launch_bounds__(256) void dwa_proj(
    const float* __restrict__ A, const float* __restrict__ W0,
    const float* __restrict__ bias0, float* __restrict__ out0,
    const float* __restrict__ rs) {
  __shared__ short Abs[64][128];
  __shared__ short Bbs[64][128];
  const int tid = threadIdx.x;
  const int m0 = blockIdx.x * 64;
  const int n0 = blockIdx.y * 64;

#pragma unroll
  for (int p = 0; p < 4; ++p) {
    int c = tid + p * 256;
    int row = c >> 4;
    int slot = c & 15;
    const float* src = A + (size_t)(m0 + row) * 128 + slot * 8;
    float4 f0 = *(const float4*)(src);
    float4 f1 = *(const float4*)(src + 4);
    float irs = 1.0f / rs[(size_t)(m0 + row) * 4 + (slot >> 2)];
    f0.x *= irs; f0.y *= irs; f0.z *= irs; f0.w *= irs;
    f1.x *= irs; f1.y *= irs; f1.z *= irs; f1.w *= irs;
    short8 pk;
    pk[0] = f2bf(f0.x); pk[1] = f2bf(f0.y); pk[2] = f2bf(f0.z); pk[3] = f2bf(f0.w);
    pk[4] = f2bf(f1.x); pk[5] = f2bf(f1.y); pk[6] = f2bf(f1.z); pk[7] = f2bf(f1.w);
    *(short8*)&Abs[row][(slot ^ (row & 7)) * 8] = pk;
  }
#pragma unroll
  for (int p = 0; p < 4; ++p) {
    int c = tid + p * 256;
    int row = c >> 4;
    int slot = c & 15;
    const float* src = W0 + (size_t)(n0 + row) * 128 + slot * 8;
    float4 f0 = *(const float4*)(src);
    float4 f1 = *(const float4*)(src + 4);
    short8 pk;
    pk[0] = f2bf(f0.x); pk[1] = f2bf(f0.y); pk[2] = f2bf(f0.z); pk[3] = f2bf(f0.w);
    pk[4] = f2bf(f1.x); pk[5] = f2bf(f1.y); pk[6] = f2bf(f1.z); pk[7] = f2bf(f1.w);
    *(short8*)&Bbs[row][(slot ^ (row & 7)) * 8] = pk;
  }
  __syncthreads();

  const int lane = tid & 63;
  const int wv = tid >> 6;
  const int wrow = (wv >> 1) * 32;
  const int wcol = (wv & 1) * 32;
  const int lr = lane & 15;
  const int lg = lane >> 4;

  floatx4 acc[2][2];
#pragma unroll
  for (int i = 0; i < 2; ++i)
#pragma unroll
    for (int j = 0; j < 2; ++j) acc[i][j] = {0.f, 0.f, 0.f, 0.f};

#pragma unroll
  for (int ks = 0; ks < 4; ++ks) {
    short8 af[2], bf[2];
#pragma unroll
    for (int i = 0; i < 2; ++i) {
      int r = wrow + i * 16 + lr;
      int slot = (ks * 4 + lg) ^ (r & 7);
      af[i] = *(const short8*)&Abs[r][slot * 8];
    }
#pragma unroll
    for (int j = 0; j < 2; ++j) {
      int r = wcol + j * 16 + lr;
      int slot = (ks * 4 + lg) ^ (r & 7);
      bf[j] = *(const short8*)&Bbs[r][slot * 8];
    }
#pragma unroll
    for (int i = 0; i < 2; ++i)
#pragma unroll
      for (int j = 0; j < 2; ++j)
        acc[i][j] = __builtin_amdgcn_mfma_f32_16x16x32_bf16(af[i], bf[j],
                                                            acc[i][j], 0, 0, 0);
  }

#pragma unroll
  for (int i = 0; i < 2; ++i) {
#pragma unroll
    for (int reg = 0; reg < 4; ++reg) {
      int grow = m0 + wrow + i * 16 + lg * 4 + reg;
#pragma unroll
      for (int j = 0; j < 2; ++j) {
        int gcol = n0 + wcol + j * 16 + lr;
        out0[(size_t)grow * 128 + gcol] = acc[i][j][reg] + bias0[gcol];
      }
    }
  }
}

// ---------------------------------------------------------------------------
extern "C" void kernel_launch(void* const* d_in, const int* in_sizes, int n_in,
                              void* d_out, int out_size, void* d_ws,
                              size_t ws_size, hipStream_t stream) {
  const float* x = (const float*)d_in[0];
  const float* w_qkv = (const float*)d_in[1];
  const float* b_qkv = (const float*)d_in[2];
  const float* w_off = (const float*)d_in[3];
  const float* b_off = (const float*)d_in[4];
  const float* rpb = (const float*)d_in[5];
  const float* w_proj = (const float*)d_in[6];
  const float* b_proj = (const float*)d_in[7];
  float* out = (float*)d_out;

  char* ws = (char*)d_ws;
  short* qkv_bf = (short*)ws;                              // 12544*384*2B
  __half* off_h = (__half*)(ws + (size_t)MROWS * 384 * 2); // 12544*392*2B
  float* attn_out = (float*)(ws + (size_t)MROWS * 384 * 2 +
                             (size_t)MROWS * 392 * 2);     // 12544*128*4B
  float* rs_buf = attn_out + (size_t)MROWS * 128;          // 12544*4

  dwa_gemm0<<<dim3(196, 5), 256, 0, stream>>>(x, w_qkv, w_off, b_qkv, b_off,
                                              qkv_bf, off_h);
  dwa_attn<<<2048, 256, 0, stream>>>(qkv_bf, off_h, rpb, attn_out, rs_buf);
  dwa_proj<<<dim3(196, 2), 256, 0, stream>>>(attn_out, w_proj, b_proj, out,
                                             rs_buf);
}

// Round 18
// 67.924 us; speedup vs baseline: 2.6287x; 1.3480x over previous
//
#include <hip/hip_runtime.h>
#include <hip/hip_bf16.h>
#include <hip/hip_fp16.h>
#include <stdint.h>

// Problem constants
#define BATCH 256
#define NPOS 49
#define CCH 128
#define KWIN 7
#define HEADS 4
#define K2 49
#define HD 32
#define MROWS (BATCH * NPOS)         // 12544
#define QSCALE 0.17677669529663687f  // 32^-0.5

using short8 = __attribute__((ext_vector_type(8))) short;
using floatx4 = __attribute__((ext_vector_type(4))) float;

static __device__ inline short f2bf(float x) {
  uint32_t u = __float_as_uint(x);
  uint32_t r = (u + 0x7fffu + ((u >> 16) & 1u)) >> 16;
  return (short)r;
}

// ---------------------------------------------------------------------------
// GEMM 0 (r15): x @ [w_qkv;w_off]^T -> qkv_bf (bf16, q pre-scaled) + off_h.
// ---------------------------------------------------------------------------
__global__ __launch_bounds__(256) void dwa_gemm0(
    const float* __restrict__ x, const float* __restrict__ w_qkv,
    const float* __restrict__ w_off, const float* __restrict__ b_qkv,
    const float* __restrict__ b_off, short* __restrict__ qkv_bf,
    __half* __restrict__ off_h) {
  __shared__ short Abs[64][128];
  __shared__ short Bbs[64][128];
  const int tid = threadIdx.x;
  const int m0 = blockIdx.x * 64;

#pragma unroll
  for (int p = 0; p < 4; ++p) {
    int c = tid + p * 256;
    int row = c >> 4;
    int slot = c & 15;
    const float* src = x + (size_t)(m0 + row) * 128 + slot * 8;
    float4 f0 = *(const float4*)(src);
    float4 f1 = *(const float4*)(src + 4);
    short8 pk;
    pk[0] = f2bf(f0.x); pk[1] = f2bf(f0.y); pk[2] = f2bf(f0.z); pk[3] = f2bf(f0.w);
    pk[4] = f2bf(f1.x); pk[5] = f2bf(f1.y); pk[6] = f2bf(f1.z); pk[7] = f2bf(f1.w);
    *(short8*)&Abs[row][(slot ^ (row & 7)) * 8] = pk;
  }

  const int lane = tid & 63;
  const int wv = tid >> 6;
  const int wrow = (wv >> 1) * 32;
  const int wcol = (wv & 1) * 32;
  const int lr = lane & 15;
  const int lg = lane >> 4;

#pragma unroll
  for (int t = 0; t < 3; ++t) {
    const int ntile = blockIdx.y + 5 * t;
    if (ntile >= 13) break;
    const int n0 = ntile * 64;
#pragma unroll
    for (int p = 0; p < 4; ++p) {
      int c = tid + p * 256;
      int row = c >> 4;
      int slot = c & 15;
      int colg = n0 + row;
      float4 f0 = make_float4(0.f, 0.f, 0.f, 0.f), f1 = f0;
      if (colg < 384) {
        const float* src = w_qkv + (size_t)colg * 128 + slot * 8;
        f0 = *(const float4*)(src);
        f1 = *(const float4*)(src + 4);
      } else if (colg < 776) {
        const float* src = w_off + (size_t)(colg - 384) * 128 + slot * 8;
        f0 = *(const float4*)(src);
        f1 = *(const float4*)(src + 4);
      }
      short8 pk;
      pk[0] = f2bf(f0.x); pk[1] = f2bf(f0.y); pk[2] = f2bf(f0.z); pk[3] = f2bf(f0.w);
      pk[4] = f2bf(f1.x); pk[5] = f2bf(f1.y); pk[6] = f2bf(f1.z); pk[7] = f2bf(f1.w);
      *(short8*)&Bbs[row][(slot ^ (row & 7)) * 8] = pk;
    }
    __syncthreads();

    floatx4 acc[2][2];
#pragma unroll
    for (int i = 0; i < 2; ++i)
#pragma unroll
      for (int j = 0; j < 2; ++j) acc[i][j] = {0.f, 0.f, 0.f, 0.f};
#pragma unroll
    for (int ks = 0; ks < 4; ++ks) {
      short8 af[2], bf[2];
#pragma unroll
      for (int i = 0; i < 2; ++i) {
        int r = wrow + i * 16 + lr;
        int slot = (ks * 4 + lg) ^ (r & 7);
        af[i] = *(const short8*)&Abs[r][slot * 8];
      }
#pragma unroll
      for (int j = 0; j < 2; ++j) {
        int r = wcol + j * 16 + lr;
        int slot = (ks * 4 + lg) ^ (r & 7);
        bf[j] = *(const short8*)&Bbs[r][slot * 8];
      }
#pragma unroll
      for (int i = 0; i < 2; ++i)
#pragma unroll
        for (int j = 0; j < 2; ++j)
          acc[i][j] = __builtin_amdgcn_mfma_f32_16x16x32_bf16(af[i], bf[j],
                                                              acc[i][j], 0, 0, 0);
    }
#pragma unroll
    for (int i = 0; i < 2; ++i) {
#pragma unroll
      for (int reg = 0; reg < 4; ++reg) {
        int grow = m0 + wrow + i * 16 + lg * 4 + reg;
#pragma unroll
        for (int j = 0; j < 2; ++j) {
          int gcol = n0 + wcol + j * 16 + lr;
          float v = acc[i][j][reg];
          if (gcol < 384) {
            float sc = (gcol < 128) ? QSCALE : 1.0f;
            qkv_bf[(size_t)grow * 384 + gcol] = f2bf((v + b_qkv[gcol]) * sc);
          } else if (gcol < 776) {
            off_h[(size_t)grow * 392 + (gcol - 384)] =
                __float2half(v + b_off[gcol - 384]);
          }
        }
      }
    }
    __syncthreads();
  }
}

// ---------------------------------------------------------------------------
// Deformable window attention, ATOMIC-FREE scatter (r16/r17 verdict: LDS
// atomicAdd costs ~240cy/instr regardless of collisions -> count must be 0).
// One block per (b,h,half), 256 threads = 4 waves, 3 barriers.
// P3 rewrite: wave w owns rows n = w, w+4, ... (sequential). Per row:
//   - 49 lanes compute pe + 4 (cell,val); duplicate cells (clamped, weight
//     exactly 0) redirected to trash rows 49/50/51 -> per-lane cells DISTINCT.
//   - PLAIN bf16 stores into per-wave scratch scr[cell][lane] (lane column
//     unique -> no races by construction). Chunk-XOR swizzle (^row&7).
//   - reduce A2row[m] = sum_lane scr[m][lane] via ones-B MFMA (4 tiles x
//     K=64); col-0 lanes write A2b[n][m] (m>48 -> 0). In-order DS pipe +
//     lgkmcnt(0)+sched_barrier makes wave-local write->read safe.
// LDS 46.7 KB -> 3 blocks/CU. P4 deleted.
// ---------------------------------------------------------------------------
__global__ __launch_bounds__(256, 3) void dwa_attn(
    const short* __restrict__ qkv_bf, const __half* __restrict__ off_h,
    const float* __restrict__ rpb, float* __restrict__ attn_out,
    float* __restrict__ rs_buf) {
  __shared__ __align__(16) short region1[3840];   // qbs(1280)+kbs(2560) / A2b
  __shared__ __align__(16) __half S0h[1356];      // [26][52] fp16 + pad
  __shared__ __align__(16) short vbT[32 * 72];    // bf16 v^T [d][m]
  __shared__ __align__(16) short scr_all[4 * 4096];  // per-wave [64][64] bf16

  short* qbs = region1;          // [32][40] bf16
  short* kbs = region1 + 1280;   // [64][40] bf16
  short* A2b = region1;          // [32][72] bf16 (aliases qbs/kbs after P2)

  const int bid = blockIdx.x;
  const int swz = (bid & 7) * 256 + (bid >> 3);
  const int b = swz >> 3;
  const int sub = swz & 7;
  const int h = sub >> 1;
  const int half = sub & 1;
  const int bn0 = half * 25;
  const int rcnt = half ? 24 : 25;

  const int tid = threadIdx.x;
  const int lane = tid & 63;
  const int wv = tid >> 6;
  const int lr = lane & 15;
  const int lg = lane >> 4;
  short* scr = scr_all + wv * 4096;  // this wave's [64][64] bf16 scratch

  // per-lane k2 constants (lane = k2)
  const int kk2 = (lane < 49) ? lane : 48;
  const int ky = kk2 / 7;
  const int kx = kk2 - ky * 7;
  const float bias_r = rpb[h * 169 + (ky + 3) * 13 + (kx + 3)];

  // ---- prefetch offsets for my wave's rows (<=7) ----
  const __half* offp = off_h + (size_t)(b * 49) * 392 + h * 98;
  float2 offr[7];
#pragma unroll
  for (int i = 0; i < 7; ++i) {
    int nl = wv + 4 * i;
    if (nl < rcnt && lane < 49) {
      __half2 o2 =
          *(const __half2*)(offp + (size_t)(bn0 + nl) * 392 + lane * 2);
      offr[i] = __half22float2(o2);
    } else {
      offr[i] = make_float2(0.f, 0.f);
    }
  }

  // ---- P1 stage (pure copies) ----
  {
    short8 zz = {0, 0, 0, 0, 0, 0, 0, 0};
    {
      int r = tid >> 2, c4 = tid & 3;
      short8 pk = zz;
      if (r < 49)
        pk = *(const short8*)(qkv_bf + (size_t)(b * 49 + r) * 384 + 128 +
                              h * 32 + c4 * 8);
      *(short8*)&kbs[r * 40 + c4 * 8] = pk;
    }
    if (tid < 128) {
      int r = tid >> 2, c4 = tid & 3;
      short8 pk = zz;
      if (r < rcnt)
        pk = *(const short8*)(qkv_bf + (size_t)(b * 49 + bn0 + r) * 384 +
                              h * 32 + c4 * 8);
      *(short8*)&qbs[r * 40 + c4 * 8] = pk;
    }
    const short* vbase = qkv_bf + (size_t)(b * 49) * 384 + 256 + h * 32;
#pragma unroll
    for (int it = 0; it < 7; ++it) {
      int i = tid + it * 256;
      if (i < 1568) {
        int n = i >> 5;
        int d = i & 31;
        vbT[d * 72 + n] = vbase[(size_t)n * 384 + d];
      }
    }
    for (int i = tid; i < 480; i += 256) {  // zero vbT cols 49..63, all d
      int d = i / 15;
      int j = i - d * 15;
      vbT[d * 72 + 49 + j] = 0;
    }
    if (tid < 16) S0h[25 * 52 + tid] = __float2half(0.f);
    // zero this wave's scratch rows 52..63 ONCE (rows 0..51 zeroed per row)
    for (int c = lane; c < 96; c += 64) *(short8*)&scr[3328 + c * 8] = zz;
  }
  __syncthreads();  // B1

  // ---- P2: S0h[n][m] = k_m . q_n via mfma(A=k, B=q); fp16 b64 writes ----
  {
    const int mt = wv;
    short8 af = *(const short8*)&kbs[(mt * 16 + lr) * 40 + lg * 8];
    floatx4 z = {0.f, 0.f, 0.f, 0.f};
#pragma unroll
    for (int nt = 0; nt < 2; ++nt) {
      short8 bf = *(const short8*)&qbs[(nt * 16 + lr) * 40 + lg * 8];
      floatx4 c = __builtin_amdgcn_mfma_f32_16x16x32_bf16(af, bf, z, 0, 0, 0);
      int n = nt * 16 + lr;
      int mbase = mt * 16 + lg * 4;
      if (n < 26 && mbase < 52) {  // both guards required (row pitch 52)
        short4 pk;
        pk.x = (short)__half_as_ushort(__float2half(c[0]));
        pk.y = (short)__half_as_ushort(__float2half(c[1]));
        pk.z = (short)__half_as_ushort(__float2half(c[2]));
        pk.w = (short)__half_as_ushort(__float2half(c[3]));
        *(short4*)&S0h[n * 52 + mbase] = pk;
      }
    }
  }
  __syncthreads();  // B2 (q/k region dead; A2b region writable per-wave)

  // ---- P3: per-wave row loop -- scores + plain scatter + MFMA reduce ----
  {
    short8 zz = {0, 0, 0, 0, 0, 0, 0, 0};
    short8 bones;
#pragma unroll
    for (int u = 0; u < 8; ++u) bones[u] = (lr == 0) ? (short)0x3F80 : (short)0;
    const int lchunk = lane >> 3;   // scatter column chunk
    const int lsub = lane & 7;

#pragma unroll
    for (int i = 0; i < 7; ++i) {
      const int nl = wv + 4 * i;
      if (nl >= rcnt) break;
      // zero scratch rows 0..51 (416 chunks of 8 bf16)
      for (int c = lane; c < 416; c += 64) *(short8*)&scr[c * 8] = zz;
      // scatter: plain bf16 stores, per-lane distinct cells
      if (lane < 49) {
        const int gn = bn0 + nl;
        const int iy = (int)((unsigned)gn / 7u);
        const int ix = gn - iy * 7;
        float py = fminf(fmaxf((float)(iy + ky - 3) + offr[i].x, 0.f), 6.f);
        float px = fminf(fmaxf((float)(ix + kx - 3) + offr[i].y, 0.f), 6.f);
        float y0f = floorf(py), x0f = floorf(px);
        float wy = py - y0f, wx = px - x0f;
        int y0 = (int)y0f, x0 = (int)x0f;
        int c00 = y0 * 7 + x0;
        int sbase = nl * 52 + c00;
        float s00 = __half2float(S0h[sbase]);
        float s01 = __half2float(S0h[sbase + 1]);
        float s10 = __half2float(S0h[sbase + 7]);
        float s11 = __half2float(S0h[sbase + 8]);
        float w00 = (1.f - wy) * (1.f - wx);
        float w01 = (1.f - wy) * wx;
        float w10 = wy * (1.f - wx);
        float w11 = wy * wx;
        float s = w00 * s00 + w01 * s01 + w10 * s10 + w11 * s11 + bias_r;
        float pe = __expf(s);
        // duplicate cells (weight==0 exactly) -> trash rows 49/50/51
        bool xc = (x0 == 6), yc = (y0 == 6);
        int c01 = xc ? 49 : c00 + 1;
        int c10 = yc ? 50 : c00 + 7;
        int c11 = (xc || yc) ? 51 : c00 + 8;
        scr[c00 * 64 + ((lchunk ^ (c00 & 7)) * 8) + lsub] = f2bf(pe * w00);
        scr[c01 * 64 + ((lchunk ^ (c01 & 7)) * 8) + lsub] = f2bf(pe * w01);
        scr[c10 * 64 + ((lchunk ^ (c10 & 7)) * 8) + lsub] = f2bf(pe * w10);
        scr[c11 * 64 + ((lchunk ^ (c11 & 7)) * 8) + lsub] = f2bf(pe * w11);
      }
      // wave-local handoff: in-order DS pipe; drain + pin schedule
      asm volatile("s_waitcnt lgkmcnt(0)" ::: "memory");
      __builtin_amdgcn_sched_barrier(0);
      // reduce: A2row[m] = sum over 64 cols via ones-B MFMA
#pragma unroll
      for (int tile = 0; tile < 4; ++tile) {
        floatx4 cacc = {0.f, 0.f, 0.f, 0.f};
#pragma unroll
        for (int ks = 0; ks < 2; ++ks) {
          int row = tile * 16 + lr;
          int chunk = ks * 4 + lg;
          short8 af =
              *(const short8*)&scr[row * 64 + ((chunk ^ (row & 7)) * 8)];
          cacc = __builtin_amdgcn_mfma_f32_16x16x32_bf16(af, bones, cacc,
                                                         0, 0, 0);
        }
        if ((lane & 15) == 0) {
          int mb = tile * 16 + (lane >> 4) * 4;
#pragma unroll
          for (int reg = 0; reg < 4; ++reg) {
            int m = mb + reg;
            A2b[nl * 72 + m] = (m <= 48) ? f2bf(cacc[reg]) : (short)0;
          }
        }
      }
      __builtin_amdgcn_sched_barrier(0);  // reduce reads before next zeroing
    }
  }
  __syncthreads();  // B3

  // ---- P5: out + rowsum via MFMA ----
  {
    const int nt = wv & 1;
    const int dt = wv >> 1;
    floatx4 acc = {0.f, 0.f, 0.f, 0.f};
    floatx4 accS = {0.f, 0.f, 0.f, 0.f};
    short8 bones;
#pragma unroll
    for (int u = 0; u < 8; ++u) bones[u] = (lr == 0) ? (short)0x3F80 : (short)0;
#pragma unroll
    for (int ks = 0; ks < 2; ++ks) {
      short8 af = *(const short8*)&A2b[(nt * 16 + lr) * 72 + ks * 32 + lg * 8];
      short8 bf = *(const short8*)&vbT[(dt * 16 + lr) * 72 + ks * 32 + lg * 8];
      acc = __builtin_amdgcn_mfma_f32_16x16x32_bf16(af, bf, acc, 0, 0, 0);
      if (dt == 0)
        accS = __builtin_amdgcn_mfma_f32_16x16x32_bf16(af, bones, accS, 0, 0, 0);
    }
    const int d = dt * 16 + lr;
#pragma unroll
    for (int reg = 0; reg < 4; ++reg) {
      int n = nt * 16 + lg * 4 + reg;
      if (n < rcnt) {
        int grow = b * 49 + bn0 + n;
        attn_out[(size_t)grow * 128 + h * 32 + d] = acc[reg];
        if (dt == 0 && lr == 0) rs_buf[(size_t)grow * 4 + h] = accS[reg];
      }
    }
  }
}

// ---------------------------------------------------------------------------
// Proj GEMM: out = diag(1/rs per head) * attn_out @ w_proj^T + b_proj
// ---------------------------------------------------------------------------
__global__ __launch_bounds__(256) void dwa_proj(
    const float* __restrict__ A, const float* __restrict__ W0,
    const float* __restrict__ bias0, float* __restrict__ out0,
    const float* __restrict__ rs) {
  __shared__ short Abs[64][128];
  __shared__ short Bbs[64][128];
  const int tid = threadIdx.x;
  const int m0 = blockIdx.x * 64;
  const int n0 = blockIdx.y * 64;

#pragma unroll
  for (int p = 0; p < 4; ++p) {
    int c = tid + p * 256;
    int row = c >> 4;
    int slot = c & 15;
    const float* src = A + (size_t)(m0 + row) * 128 + slot * 8;
    float4 f0 = *(const float4*)(src);
    float4 f1 = *(const float4*)(src + 4);
    float irs = 1.0f / rs[(size_t)(m0 + row) * 4 + (slot >> 2)];
    f0.x *= irs; f0.y *= irs; f0.z *= irs; f0.w *= irs;
    f1.x *= irs; f1.y *= irs; f1.z *= irs; f1.w *= irs;
    short8 pk;
    pk[0] = f2bf(f0.x); pk[1] = f2bf(f0.y); pk[2] = f2bf(f0.z); pk[3] = f2bf(f0.w);
    pk[4] = f2bf(f1.x); pk[5] = f2bf(f1.y); pk[6] = f2bf(f1.z); pk[7] = f2bf(f1.w);
    *(short8*)&Abs[row][(slot ^ (row & 7)) * 8] = pk;
  }
#pragma unroll
  for (int p = 0; p < 4; ++p) {
    int c = tid + p * 256;
    int row = c >> 4;
    int slot = c & 15;
    const float* src = W0 + (size_t)(n0 + row) * 128 + slot * 8;
    float4 f0 = *(const float4*)(src);
    float4 f1 = *(const float4*)(src + 4);
    short8 pk;
    pk[0] = f2bf(f0.x); pk[1] = f2bf(f0.y); pk[2] = f2bf(f0.z); pk[3] = f2bf(f0.w);
    pk[4] = f2bf(f1.x); pk[5] = f2bf(f1.y); pk[6] = f2bf(f1.z); pk[7] = f2bf(f1.w);
    *(short8*)&Bbs[row][(slot ^ (row & 7)) * 8] = pk;
  }
  __syncthreads();

  const int lane = tid & 63;
  const int wv = tid >> 6;
  const int wrow = (wv >> 1) * 32;
  const int wcol = (wv & 1) * 32;
  const int lr = lane & 15;
  const int lg = lane >> 4;

  floatx4 acc[2][2];
#pragma unroll
  for (int i = 0; i < 2; ++i)
#pragma unroll
    for (int j = 0; j < 2; ++j) acc[i][j] = {0.f, 0.f, 0.f, 0.f};

#pragma unroll
  for (int ks = 0; ks < 4; ++ks) {
    short8 af[2], bf[2];
#pragma unroll
    for (int i = 0; i < 2; ++i) {
      int r = wrow + i * 16 + lr;
      int slot = (ks * 4 + lg) ^ (r & 7);
      af[i] = *(const short8*)&Abs[r][slot * 8];
    }
#pragma unroll
    for (int j = 0; j < 2; ++j) {
      int r = wcol + j * 16 + lr;
      int slot = (ks * 4 + lg) ^ (r & 7);
      bf[j] = *(const short8*)&Bbs[r][slot * 8];
    }
#pragma unroll
    for (int i = 0; i < 2; ++i)
#pragma unroll
      for (int j = 0; j < 2; ++j)
        acc[i][j] = __builtin_amdgcn_mfma_f32_16x16x32_bf16(af[i], bf[j],
                                                            acc[i][j], 0, 0, 0);
  }

#pragma unroll
  for (int i = 0; i < 2; ++i) {
#pragma unroll
    for (int reg = 0; reg < 4; ++reg) {
      int grow = m0 + wrow + i * 16 + lg * 4 + reg;
#pragma unroll
      for (int j = 0; j < 2; ++j) {
        int gcol = n0 + wcol + j * 16 + lr;
        out0[(size_t)grow * 128 + gcol] = acc[i][j][reg] + bias0[gcol];
      }
    }
  }
}

// ---------------------------------------------------------------------------
extern "C" void kernel_launch(void* const* d_in, const int* in_sizes, int n_in,
                              void* d_out, int out_size, void* d_ws,
                              size_t ws_size, hipStream_t stream) {
  const float* x = (const float*)d_in[0];
  const float* w_qkv = (const float*)d_in[1];
  const float* b_qkv = (const float*)d_in[2];
  const float* w_off = (const float*)d_in[3];
  const float* b_off = (const float*)d_in[4];
  const float* rpb = (const float*)d_in[5];
  const float* w_proj = (const float*)d_in[6];
  const float* b_proj = (const float*)d_in[7];
  float* out = (float*)d_out;

  char* ws = (char*)d_ws;
  short* qkv_bf = (short*)ws;                              // 12544*384*2B
  __half* off_h = (__half*)(ws + (size_t)MROWS * 384 * 2); // 12544*392*2B
  float* attn_out = (float*)(ws + (size_t)MROWS * 384 * 2 +
                             (size_t)MROWS * 392 * 2);     // 12544*128*4B
  float* rs_buf = attn_out + (size_t)MROWS * 128;          // 12544*4

  dwa_gemm0<<<dim3(196, 5), 256, 0, stream>>>(x, w_qkv, w_off, b_qkv, b_off,
                                              qkv_bf, off_h);
  dwa_attn<<<2048, 256, 0, stream>>>(qkv_bf, off_h, rpb, attn_out, rs_buf);
  dwa_proj<<<dim3(196, 2), 256, 0, stream>>>(attn_out, w_proj, b_proj, out,
                                             rs_buf);
}

// Round 19
// 57.778 us; speedup vs baseline: 3.0903x; 1.1756x over previous
//
#include <hip/hip_runtime.h>
#include <hip/hip_bf16.h>
#include <hip/hip_fp16.h>
#include <stdint.h>

// Problem constants
#define BATCH 256
#define NPOS 49
#define CCH 128
#define KWIN 7
#define HEADS 4
#define K2 49
#define HD 32
#define MROWS (BATCH * NPOS)         // 12544
#define QSCALE 0.17677669529663687f  // 32^-0.5

using short8 = __attribute__((ext_vector_type(8))) short;
using floatx4 = __attribute__((ext_vector_type(4))) float;

static __device__ inline short f2bf(float x) {
  uint32_t u = __float_as_uint(x);
  uint32_t r = (u + 0x7fffu + ((u >> 16) & 1u)) >> 16;
  return (short)r;
}

// ---------------------------------------------------------------------------
// GEMM 0 (r15): x @ [w_qkv;w_off]^T -> qkv_bf (bf16, q pre-scaled) + off_h.
// ---------------------------------------------------------------------------
__global__ __launch_bounds__(256) void dwa_gemm0(
    const float* __restrict__ x, const float* __restrict__ w_qkv,
    const float* __restrict__ w_off, const float* __restrict__ b_qkv,
    const float* __restrict__ b_off, short* __restrict__ qkv_bf,
    __half* __restrict__ off_h) {
  __shared__ short Abs[64][128];
  __shared__ short Bbs[64][128];
  const int tid = threadIdx.x;
  const int m0 = blockIdx.x * 64;

#pragma unroll
  for (int p = 0; p < 4; ++p) {
    int c = tid + p * 256;
    int row = c >> 4;
    int slot = c & 15;
    const float* src = x + (size_t)(m0 + row) * 128 + slot * 8;
    float4 f0 = *(const float4*)(src);
    float4 f1 = *(const float4*)(src + 4);
    short8 pk;
    pk[0] = f2bf(f0.x); pk[1] = f2bf(f0.y); pk[2] = f2bf(f0.z); pk[3] = f2bf(f0.w);
    pk[4] = f2bf(f1.x); pk[5] = f2bf(f1.y); pk[6] = f2bf(f1.z); pk[7] = f2bf(f1.w);
    *(short8*)&Abs[row][(slot ^ (row & 7)) * 8] = pk;
  }

  const int lane = tid & 63;
  const int wv = tid >> 6;
  const int wrow = (wv >> 1) * 32;
  const int wcol = (wv & 1) * 32;
  const int lr = lane & 15;
  const int lg = lane >> 4;

#pragma unroll
  for (int t = 0; t < 3; ++t) {
    const int ntile = blockIdx.y + 5 * t;
    if (ntile >= 13) break;
    const int n0 = ntile * 64;
#pragma unroll
    for (int p = 0; p < 4; ++p) {
      int c = tid + p * 256;
      int row = c >> 4;
      int slot = c & 15;
      int colg = n0 + row;
      float4 f0 = make_float4(0.f, 0.f, 0.f, 0.f), f1 = f0;
      if (colg < 384) {
        const float* src = w_qkv + (size_t)colg * 128 + slot * 8;
        f0 = *(const float4*)(src);
        f1 = *(const float4*)(src + 4);
      } else if (colg < 776) {
        const float* src = w_off + (size_t)(colg - 384) * 128 + slot * 8;
        f0 = *(const float4*)(src);
        f1 = *(const float4*)(src + 4);
      }
      short8 pk;
      pk[0] = f2bf(f0.x); pk[1] = f2bf(f0.y); pk[2] = f2bf(f0.z); pk[3] = f2bf(f0.w);
      pk[4] = f2bf(f1.x); pk[5] = f2bf(f1.y); pk[6] = f2bf(f1.z); pk[7] = f2bf(f1.w);
      *(short8*)&Bbs[row][(slot ^ (row & 7)) * 8] = pk;
    }
    __syncthreads();

    floatx4 acc[2][2];
#pragma unroll
    for (int i = 0; i < 2; ++i)
#pragma unroll
      for (int j = 0; j < 2; ++j) acc[i][j] = {0.f, 0.f, 0.f, 0.f};
#pragma unroll
    for (int ks = 0; ks < 4; ++ks) {
      short8 af[2], bf[2];
#pragma unroll
      for (int i = 0; i < 2; ++i) {
        int r = wrow + i * 16 + lr;
        int slot = (ks * 4 + lg) ^ (r & 7);
        af[i] = *(const short8*)&Abs[r][slot * 8];
      }
#pragma unroll
      for (int j = 0; j < 2; ++j) {
        int r = wcol + j * 16 + lr;
        int slot = (ks * 4 + lg) ^ (r & 7);
        bf[j] = *(const short8*)&Bbs[r][slot * 8];
      }
#pragma unroll
      for (int i = 0; i < 2; ++i)
#pragma unroll
        for (int j = 0; j < 2; ++j)
          acc[i][j] = __builtin_amdgcn_mfma_f32_16x16x32_bf16(af[i], bf[j],
                                                              acc[i][j], 0, 0, 0);
    }
#pragma unroll
    for (int i = 0; i < 2; ++i) {
#pragma unroll
      for (int reg = 0; reg < 4; ++reg) {
        int grow = m0 + wrow + i * 16 + lg * 4 + reg;
#pragma unroll
        for (int j = 0; j < 2; ++j) {
          int gcol = n0 + wcol + j * 16 + lr;
          float v = acc[i][j][reg];
          if (gcol < 384) {
            float sc = (gcol < 128) ? QSCALE : 1.0f;
            qkv_bf[(size_t)grow * 384 + gcol] = f2bf((v + b_qkv[gcol]) * sc);
          } else if (gcol < 776) {
            off_h[(size_t)grow * 392 + (gcol - 384)] =
                __float2half(v + b_off[gcol - 384]);
          }
        }
      }
    }
    __syncthreads();
  }
}

// ---------------------------------------------------------------------------
// Deformable window attention, atomic-free scatter (r18) + r19 refinements:
//  - scr zeroed ONCE per wave in P1; per row each lane re-zeroes only its
//    own 4 slots after the reduce (saves ~6.5 wide stores + ~40 VALU/row).
//  - single trash row 49 (clamped-duplicate weights are exactly 0; same-lane
//    collisions store identical 0s -> benign). scr shrinks to 50 rows/wave.
//  - LDS 40600 B <= 40KB -> 4 blocks/CU -> exactly 2 scheduling rounds.
//  - reduce tile 3 reads rows 50..63 out-of-wave-scr (neighbor data/UB-zero);
//    MFMA row-sums are independent and the m<=48 gate discards them.
//    scr_all declared FIRST so OOB reads stay inside the block's LDS.
// ---------------------------------------------------------------------------
__global__ __launch_bounds__(256, 4) void dwa_attn(
    const short* __restrict__ qkv_bf, const __half* __restrict__ off_h,
    const float* __restrict__ rpb, float* __restrict__ attn_out,
    float* __restrict__ rs_buf) {
  __shared__ __align__(16) short scr_all[4 * 3200];  // per-wave [50][64] bf16
  __shared__ __align__(16) short region1[3840];   // qbs(1280)+kbs(2560) / A2b
  __shared__ __align__(16) __half S0h[1356];      // [26][52] fp16 + pad
  __shared__ __align__(16) short vbT[32 * 72];    // bf16 v^T [d][m]

  short* qbs = region1;          // [32][40] bf16
  short* kbs = region1 + 1280;   // [64][40] bf16
  short* A2b = region1;          // [32][72] bf16 (aliases qbs/kbs after P2)

  const int bid = blockIdx.x;
  const int swz = (bid & 7) * 256 + (bid >> 3);
  const int b = swz >> 3;
  const int sub = swz & 7;
  const int h = sub >> 1;
  const int half = sub & 1;
  const int bn0 = half * 25;
  const int rcnt = half ? 24 : 25;

  const int tid = threadIdx.x;
  const int lane = tid & 63;
  const int wv = tid >> 6;
  const int lr = lane & 15;
  const int lg = lane >> 4;
  short* scr = scr_all + wv * 3200;  // this wave's [50][64] bf16 scratch

  // per-lane k2 constants (lane = k2)
  const int kk2 = (lane < 49) ? lane : 48;
  const int ky = kk2 / 7;
  const int kx = kk2 - ky * 7;
  const float bias_r = rpb[h * 169 + (ky + 3) * 13 + (kx + 3)];

  // ---- prefetch offsets for my wave's rows (<=7) ----
  const __half* offp = off_h + (size_t)(b * 49) * 392 + h * 98;
  float2 offr[7];
#pragma unroll
  for (int i = 0; i < 7; ++i) {
    int nl = wv + 4 * i;
    if (nl < rcnt && lane < 49) {
      __half2 o2 =
          *(const __half2*)(offp + (size_t)(bn0 + nl) * 392 + lane * 2);
      offr[i] = __half22float2(o2);
    } else {
      offr[i] = make_float2(0.f, 0.f);
    }
  }

  // ---- P1 stage (pure copies) + full scr zero (once) ----
  {
    short8 zz = {0, 0, 0, 0, 0, 0, 0, 0};
    {
      int r = tid >> 2, c4 = tid & 3;
      short8 pk = zz;
      if (r < 49)
        pk = *(const short8*)(qkv_bf + (size_t)(b * 49 + r) * 384 + 128 +
                              h * 32 + c4 * 8);
      *(short8*)&kbs[r * 40 + c4 * 8] = pk;
    }
    if (tid < 128) {
      int r = tid >> 2, c4 = tid & 3;
      short8 pk = zz;
      if (r < rcnt)
        pk = *(const short8*)(qkv_bf + (size_t)(b * 49 + bn0 + r) * 384 +
                              h * 32 + c4 * 8);
      *(short8*)&qbs[r * 40 + c4 * 8] = pk;
    }
    const short* vbase = qkv_bf + (size_t)(b * 49) * 384 + 256 + h * 32;
#pragma unroll
    for (int it = 0; it < 7; ++it) {
      int i = tid + it * 256;
      if (i < 1568) {
        int n = i >> 5;
        int d = i & 31;
        vbT[d * 72 + n] = vbase[(size_t)n * 384 + d];
      }
    }
    for (int i = tid; i < 480; i += 256) {  // zero vbT cols 49..63, all d
      int d = i / 15;
      int j = i - d * 15;
      vbT[d * 72 + 49 + j] = 0;
    }
    if (tid < 16) S0h[25 * 52 + tid] = __float2half(0.f);
    // zero this wave's FULL scr (50 rows x 64 = 400 chunks of 8)
    for (int c = lane; c < 400; c += 64) *(short8*)&scr[c * 8] = zz;
  }
  __syncthreads();  // B1

  // ---- P2: S0h[n][m] = k_m . q_n via mfma(A=k, B=q); fp16 b64 writes ----
  {
    const int mt = wv;
    short8 af = *(const short8*)&kbs[(mt * 16 + lr) * 40 + lg * 8];
    floatx4 z = {0.f, 0.f, 0.f, 0.f};
#pragma unroll
    for (int nt = 0; nt < 2; ++nt) {
      short8 bf = *(const short8*)&qbs[(nt * 16 + lr) * 40 + lg * 8];
      floatx4 c = __builtin_amdgcn_mfma_f32_16x16x32_bf16(af, bf, z, 0, 0, 0);
      int n = nt * 16 + lr;
      int mbase = mt * 16 + lg * 4;
      if (n < 26 && mbase < 52) {  // both guards required (row pitch 52)
        short4 pk;
        pk.x = (short)__half_as_ushort(__float2half(c[0]));
        pk.y = (short)__half_as_ushort(__float2half(c[1]));
        pk.z = (short)__half_as_ushort(__float2half(c[2]));
        pk.w = (short)__half_as_ushort(__float2half(c[3]));
        *(short4*)&S0h[n * 52 + mbase] = pk;
      }
    }
  }
  __syncthreads();  // B2 (q/k region dead; A2b region writable per-wave)

  // ---- P3: per-wave row loop -- scores + plain scatter + MFMA reduce ----
  {
    short8 bones;
#pragma unroll
    for (int u = 0; u < 8; ++u) bones[u] = (lr == 0) ? (short)0x3F80 : (short)0;
    const int lchunk = lane >> 3;   // scatter column chunk
    const int lsub = lane & 7;

#pragma unroll
    for (int i = 0; i < 7; ++i) {
      const int nl = wv + 4 * i;
      if (nl >= rcnt) break;
      int so0 = 0, so1 = 0, so2 = 0, so3 = 0;
      // scatter: plain bf16 stores, per-lane distinct cells (scr pre-zeroed)
      if (lane < 49) {
        const int gn = bn0 + nl;
        const int iy = (int)((unsigned)gn / 7u);
        const int ix = gn - iy * 7;
        float py = fminf(fmaxf((float)(iy + ky - 3) + offr[i].x, 0.f), 6.f);
        float px = fminf(fmaxf((float)(ix + kx - 3) + offr[i].y, 0.f), 6.f);
        float y0f = floorf(py), x0f = floorf(px);
        float wy = py - y0f, wx = px - x0f;
        int y0 = (int)y0f, x0 = (int)x0f;
        int c00 = y0 * 7 + x0;
        int sbase = nl * 52 + c00;
        float s00 = __half2float(S0h[sbase]);
        float s01 = __half2float(S0h[sbase + 1]);
        float s10 = __half2float(S0h[sbase + 7]);
        float s11 = __half2float(S0h[sbase + 8]);
        float w00 = (1.f - wy) * (1.f - wx);
        float w01 = (1.f - wy) * wx;
        float w10 = wy * (1.f - wx);
        float w11 = wy * wx;
        float s = w00 * s00 + w01 * s01 + w10 * s10 + w11 * s11 + bias_r;
        float pe = __expf(s);
        // duplicate cells (weight==0 exactly) -> single trash row 49
        // (same-lane collisions all store 0 -> benign)
        bool xc = (x0 == 6), yc = (y0 == 6);
        int c01 = xc ? 49 : c00 + 1;
        int c10 = yc ? 49 : c00 + 7;
        int c11 = (xc || yc) ? 49 : c00 + 8;
        so0 = c00 * 64 + ((lchunk ^ (c00 & 7)) * 8) + lsub;
        so1 = c01 * 64 + ((lchunk ^ (c01 & 7)) * 8) + lsub;
        so2 = c10 * 64 + ((lchunk ^ (c10 & 7)) * 8) + lsub;
        so3 = c11 * 64 + ((lchunk ^ (c11 & 7)) * 8) + lsub;
        scr[so0] = f2bf(pe * w00);
        scr[so1] = f2bf(pe * w01);
        scr[so2] = f2bf(pe * w10);
        scr[so3] = f2bf(pe * w11);
      }
      // wave-local handoff: in-order DS pipe; drain + pin schedule
      asm volatile("s_waitcnt lgkmcnt(0)" ::: "memory");
      __builtin_amdgcn_sched_barrier(0);
      // reduce: A2row[m] = sum over 64 cols via ones-B MFMA
#pragma unroll
      for (int tile = 0; tile < 4; ++tile) {
        floatx4 cacc = {0.f, 0.f, 0.f, 0.f};
#pragma unroll
        for (int ks = 0; ks < 2; ++ks) {
          int row = tile * 16 + lr;
          int chunk = ks * 4 + lg;
          short8 af =
              *(const short8*)&scr[row * 64 + ((chunk ^ (row & 7)) * 8)];
          cacc = __builtin_amdgcn_mfma_f32_16x16x32_bf16(af, bones, cacc,
                                                         0, 0, 0);
        }
        if ((lane & 15) == 0) {
          int mb = tile * 16 + (lane >> 4) * 4;
#pragma unroll
          for (int reg = 0; reg < 4; ++reg) {
            int m = mb + reg;
            A2b[nl * 72 + m] = (m <= 48) ? f2bf(cacc[reg]) : (short)0;
          }
        }
      }
      __builtin_amdgcn_sched_barrier(0);  // reduce reads before re-zero
      // re-zero own 4 slots (plain stores; ordered before next scatter by
      // may-alias store ordering + in-order DS pipe)
      if (lane < 49) {
        scr[so0] = 0;
        scr[so1] = 0;
        scr[so2] = 0;
        scr[so3] = 0;
      }
    }
  }
  __syncthreads();  // B3

  // ---- P5: out + rowsum via MFMA ----
  {
    const int nt = wv & 1;
    const int dt = wv >> 1;
    floatx4 acc = {0.f, 0.f, 0.f, 0.f};
    floatx4 accS = {0.f, 0.f, 0.f, 0.f};
    short8 bones;
#pragma unroll
    for (int u = 0; u < 8; ++u) bones[u] = (lr == 0) ? (short)0x3F80 : (short)0;
#pragma unroll
    for (int ks = 0; ks < 2; ++ks) {
      short8 af = *(const short8*)&A2b[(nt * 16 + lr) * 72 + ks * 32 + lg * 8];
      short8 bf = *(const short8*)&vbT[(dt * 16 + lr) * 72 + ks * 32 + lg * 8];
      acc = __builtin_amdgcn_mfma_f32_16x16x32_bf16(af, bf, acc, 0, 0, 0);
      if (dt == 0)
        accS = __builtin_amdgcn_mfma_f32_16x16x32_bf16(af, bones, accS, 0, 0, 0);
    }
    const int d = dt * 16 + lr;
#pragma unroll
    for (int reg = 0; reg < 4; ++reg) {
      int n = nt * 16 + lg * 4 + reg;
      if (n < rcnt) {
        int grow = b * 49 + bn0 + n;
        attn_out[(size_t)grow * 128 + h * 32 + d] = acc[reg];
        if (dt == 0 && lr == 0) rs_buf[(size_t)grow * 4 + h] = accS[reg];
      }
    }
  }
}

// ---------------------------------------------------------------------------
// Proj GEMM: out = diag(1/rs per head) * attn_out @ w_proj^T + b_proj
// ---------------------------------------------------------------------------
__global__ __launch_bounds__(256) void dwa_proj(
    const float* __restrict__ A, const float* __restrict__ W0,
    const float* __restrict__ bias0, float* __restrict__ out0,
    const float* __restrict__ rs) {
  __shared__ short Abs[64][128];
  __shared__ short Bbs[64][128];
  const int tid = threadIdx.x;
  const int m0 = blockIdx.x * 64;
  const int n0 = blockIdx.y * 64;

#pragma unroll
  for (int p = 0; p < 4; ++p) {
    int c = tid + p * 256;
    int row = c >> 4;
    int slot = c & 15;
    const float* src = A + (size_t)(m0 + row) * 128 + slot * 8;
    float4 f0 = *(const float4*)(src);
    float4 f1 = *(const float4*)(src + 4);
    float irs = 1.0f / rs[(size_t)(m0 + row) * 4 + (slot >> 2)];
    f0.x *= irs; f0.y *= irs; f0.z *= irs; f0.w *= irs;
    f1.x *= irs; f1.y *= irs; f1.z *= irs; f1.w *= irs;
    short8 pk;
    pk[0] = f2bf(f0.x); pk[1] = f2bf(f0.y); pk[2] = f2bf(f0.z); pk[3] = f2bf(f0.w);
    pk[4] = f2bf(f1.x); pk[5] = f2bf(f1.y); pk[6] = f2bf(f1.z); pk[7] = f2bf(f1.w);
    *(short8*)&Abs[row][(slot ^ (row & 7)) * 8] = pk;
  }
#pragma unroll
  for (int p = 0; p < 4; ++p) {
    int c = tid + p * 256;
    int row = c >> 4;
    int slot = c & 15;
    const float* src = W0 + (size_t)(n0 + row) * 128 + slot * 8;
    float4 f0 = *(const float4*)(src);
    float4 f1 = *(const float4*)(src + 4);
    short8 pk;
    pk[0] = f2bf(f0.x); pk[1] = f2bf(f0.y); pk[2] = f2bf(f0.z); pk[3] = f2bf(f0.w);
    pk[4] = f2bf(f1.x); pk[5] = f2bf(f1.y); pk[6] = f2bf(f1.z); pk[7] = f2bf(f1.w);
    *(short8*)&Bbs[row][(slot ^ (row & 7)) * 8] = pk;
  }
  __syncthreads();

  const int lane = tid & 63;
  const int wv = tid >> 6;
  const int wrow = (wv >> 1) * 32;
  const int wcol = (wv & 1) * 32;
  const int lr = lane & 15;
  const int lg = lane >> 4;

  floatx4 acc[2][2];
#pragma unroll
  for (int i = 0; i < 2; ++i)
#pragma unroll
    for (int j = 0; j < 2; ++j) acc[i][j] = {0.f, 0.f, 0.f, 0.f};

#pragma unroll
  for (int ks = 0; ks < 4; ++ks) {
    short8 af[2], bf[2];
#pragma unroll
    for (int i = 0; i < 2; ++i) {
      int r = wrow + i * 16 + lr;
      int slot = (ks * 4 + lg) ^ (r & 7);
      af[i] = *(const short8*)&Abs[r][slot * 8];
    }
#pragma unroll
    for (int j = 0; j < 2; ++j) {
      int r = wcol + j * 16 + lr;
      int slot = (ks * 4 + lg) ^ (r & 7);
      bf[j] = *(const short8*)&Bbs[r][slot * 8];
    }
#pragma unroll
    for (int i = 0; i < 2; ++i)
#pragma unroll
      for (int j = 0; j < 2; ++j)
        acc[i][j] = __builtin_amdgcn_mfma_f32_16x16x32_bf16(af[i], bf[j],
                                                            acc[i][j], 0, 0, 0);
  }

#pragma unroll
  for (int i = 0; i < 2; ++i) {
#pragma unroll
    for (int reg = 0; reg < 4; ++reg) {
      int grow = m0 + wrow + i * 16 + lg * 4 + reg;
#pragma unroll
      for (int j = 0; j < 2; ++j) {
        int gcol = n0 + wcol + j * 16 + lr;
        out0[(size_t)grow * 128 + gcol] = acc[i][j][reg] + bias0[gcol];
      }
    }
  }
}

// ---------------------------------------------------------------------------
extern "C" void kernel_launch(void* const* d_in, const int* in_sizes, int n_in,
                              void* d_out, int out_size, void* d_ws,
                              size_t ws_size, hipStream_t stream) {
  const float* x = (const float*)d_in[0];
  const float* w_qkv = (const float*)d_in[1];
  const float* b_qkv = (const float*)d_in[2];
  const float* w_off = (const float*)d_in[3];
  const float* b_off = (const float*)d_in[4];
  const float* rpb = (const float*)d_in[5];
  const float* w_proj = (const float*)d_in[6];
  const float* b_proj = (const float*)d_in[7];
  float* out = (float*)d_out;

  char* ws = (char*)d_ws;
  short* qkv_bf = (short*)ws;                              // 12544*384*2B
  __half* off_h = (__half*)(ws + (size_t)MROWS * 384 * 2); // 12544*392*2B
  float* attn_out = (float*)(ws + (size_t)MROWS * 384 * 2 +
                             (size_t)MROWS * 392 * 2);     // 12544*128*4B
  float* rs_buf = attn_out + (size_t)MROWS * 128;          // 12544*4

  dwa_gemm0<<<dim3(196, 5), 256, 0, stream>>>(x, w_qkv, w_off, b_qkv, b_off,
                                              qkv_bf, off_h);
  dwa_attn<<<2048, 256, 0, stream>>>(qkv_bf, off_h, rpb, attn_out, rs_buf);
  dwa_proj<<<dim3(196, 2), 256, 0, stream>>>(attn_out, w_proj, b_proj, out,
                                             rs_buf);
}

// Round 21
// 56.702 us; speedup vs baseline: 3.1489x; 1.0190x over previous
//
#include <hip/hip_runtime.h>
#include <hip/hip_bf16.h>
#include <hip/hip_fp16.h>
#include <stdint.h>

// Problem constants
#define BATCH 256
#define NPOS 49
#define CCH 128
#define KWIN 7
#define HEADS 4
#define K2 49
#define HD 32
#define MROWS (BATCH * NPOS)         // 12544
#define QSCALE 0.17677669529663687f  // 32^-0.5

using short8 = __attribute__((ext_vector_type(8))) short;
using floatx4 = __attribute__((ext_vector_type(4))) float;

static __device__ inline short f2bf(float x) {
  uint32_t u = __float_as_uint(x);
  uint32_t r = (u + 0x7fffu + ((u >> 16) & 1u)) >> 16;
  return (short)r;
}
static __device__ inline float bf2f(short s) {
  return __uint_as_float(((uint32_t)(unsigned short)s) << 16);
}

// ---------------------------------------------------------------------------
// GEMM 0 (r15): x @ [w_qkv;w_off]^T -> qkv_bf (bf16, q pre-scaled) + off_h.
// ---------------------------------------------------------------------------
__global__ __launch_bounds__(256) void dwa_gemm0(
    const float* __restrict__ x, const float* __restrict__ w_qkv,
    const float* __restrict__ w_off, const float* __restrict__ b_qkv,
    const float* __restrict__ b_off, short* __restrict__ qkv_bf,
    __half* __restrict__ off_h) {
  __shared__ short Abs[64][128];
  __shared__ short Bbs[64][128];
  const int tid = threadIdx.x;
  const int m0 = blockIdx.x * 64;

#pragma unroll
  for (int p = 0; p < 4; ++p) {
    int c = tid + p * 256;
    int row = c >> 4;
    int slot = c & 15;
    const float* src = x + (size_t)(m0 + row) * 128 + slot * 8;
    float4 f0 = *(const float4*)(src);
    float4 f1 = *(const float4*)(src + 4);
    short8 pk;
    pk[0] = f2bf(f0.x); pk[1] = f2bf(f0.y); pk[2] = f2bf(f0.z); pk[3] = f2bf(f0.w);
    pk[4] = f2bf(f1.x); pk[5] = f2bf(f1.y); pk[6] = f2bf(f1.z); pk[7] = f2bf(f1.w);
    *(short8*)&Abs[row][(slot ^ (row & 7)) * 8] = pk;
  }

  const int lane = tid & 63;
  const int wv = tid >> 6;
  const int wrow = (wv >> 1) * 32;
  const int wcol = (wv & 1) * 32;
  const int lr = lane & 15;
  const int lg = lane >> 4;

#pragma unroll
  for (int t = 0; t < 3; ++t) {
    const int ntile = blockIdx.y + 5 * t;
    if (ntile >= 13) break;
    const int n0 = ntile * 64;
#pragma unroll
    for (int p = 0; p < 4; ++p) {
      int c = tid + p * 256;
      int row = c >> 4;
      int slot = c & 15;
      int colg = n0 + row;
      float4 f0 = make_float4(0.f, 0.f, 0.f, 0.f), f1 = f0;
      if (colg < 384) {
        const float* src = w_qkv + (size_t)colg * 128 + slot * 8;
        f0 = *(const float4*)(src);
        f1 = *(const float4*)(src + 4);
      } else if (colg < 776) {
        const float* src = w_off + (size_t)(colg - 384) * 128 + slot * 8;
        f0 = *(const float4*)(src);
        f1 = *(const float4*)(src + 4);
      }
      short8 pk;
      pk[0] = f2bf(f0.x); pk[1] = f2bf(f0.y); pk[2] = f2bf(f0.z); pk[3] = f2bf(f0.w);
      pk[4] = f2bf(f1.x); pk[5] = f2bf(f1.y); pk[6] = f2bf(f1.z); pk[7] = f2bf(f1.w);
      *(short8*)&Bbs[row][(slot ^ (row & 7)) * 8] = pk;
    }
    __syncthreads();

    floatx4 acc[2][2];
#pragma unroll
    for (int i = 0; i < 2; ++i)
#pragma unroll
      for (int j = 0; j < 2; ++j) acc[i][j] = {0.f, 0.f, 0.f, 0.f};
#pragma unroll
    for (int ks = 0; ks < 4; ++ks) {
      short8 af[2], bf[2];
#pragma unroll
      for (int i = 0; i < 2; ++i) {
        int r = wrow + i * 16 + lr;
        int slot = (ks * 4 + lg) ^ (r & 7);
        af[i] = *(const short8*)&Abs[r][slot * 8];
      }
#pragma unroll
      for (int j = 0; j < 2; ++j) {
        int r = wcol + j * 16 + lr;
        int slot = (ks * 4 + lg) ^ (r & 7);
        bf[j] = *(const short8*)&Bbs[r][slot * 8];
      }
#pragma unroll
      for (int i = 0; i < 2; ++i)
#pragma unroll
        for (int j = 0; j < 2; ++j)
          acc[i][j] = __builtin_amdgcn_mfma_f32_16x16x32_bf16(af[i], bf[j],
                                                              acc[i][j], 0, 0, 0);
    }
#pragma unroll
    for (int i = 0; i < 2; ++i) {
#pragma unroll
      for (int reg = 0; reg < 4; ++reg) {
        int grow = m0 + wrow + i * 16 + lg * 4 + reg;
#pragma unroll
        for (int j = 0; j < 2; ++j) {
          int gcol = n0 + wcol + j * 16 + lr;
          float v = acc[i][j][reg];
          if (gcol < 384) {
            float sc = (gcol < 128) ? QSCALE : 1.0f;
            qkv_bf[(size_t)grow * 384 + gcol] = f2bf((v + b_qkv[gcol]) * sc);
          } else if (gcol < 776) {
            off_h[(size_t)grow * 392 + (gcol - 384)] =
                __float2half(v + b_off[gcol - 384]);
          }
        }
      }
    }
    __syncthreads();
  }
}

// ---------------------------------------------------------------------------
// Deformable window attention (r19 structure EXACTLY -- proven 57.8us pass;
// the r20 512-thread merge needed 71KB static LDS > 64KB workgroup limit and
// silently failed to launch). One block per (b,h,half); 2048 x 256 threads;
// LDS 40.6 KB -> 4 blocks/CU. Only change vs r19: output written as bf16
// (unnormalized) + f32 rowsum; proj folds 1/rs while staging.
// ---------------------------------------------------------------------------
__global__ __launch_bounds__(256, 4) void dwa_attn(
    const short* __restrict__ qkv_bf, const __half* __restrict__ off_h,
    const float* __restrict__ rpb, short* __restrict__ attn_bf,
    float* __restrict__ rs_buf) {
  __shared__ __align__(16) short scr_all[4 * 3200];  // per-wave [50][64] bf16
  __shared__ __align__(16) short region1[3840];   // qbs(1280)+kbs(2560) / A2b
  __shared__ __align__(16) __half S0h[1356];      // [26][52] fp16 + pad
  __shared__ __align__(16) short vbT[32 * 72];    // bf16 v^T [d][m]

  short* qbs = region1;          // [32][40] bf16
  short* kbs = region1 + 1280;   // [64][40] bf16
  short* A2b = region1;          // [32][72] bf16 (aliases qbs/kbs after P2)

  const int bid = blockIdx.x;
  const int swz = (bid & 7) * 256 + (bid >> 3);
  const int b = swz >> 3;
  const int sub = swz & 7;
  const int h = sub >> 1;
  const int half = sub & 1;
  const int bn0 = half * 25;
  const int rcnt = half ? 24 : 25;

  const int tid = threadIdx.x;
  const int lane = tid & 63;
  const int wv = tid >> 6;
  const int lr = lane & 15;
  const int lg = lane >> 4;
  short* scr = scr_all + wv * 3200;  // this wave's [50][64] bf16 scratch

  // per-lane k2 constants (lane = k2)
  const int kk2 = (lane < 49) ? lane : 48;
  const int ky = kk2 / 7;
  const int kx = kk2 - ky * 7;
  const float bias_r = rpb[h * 169 + (ky + 3) * 13 + (kx + 3)];

  // ---- prefetch offsets for my wave's rows (<=7) ----
  const __half* offp = off_h + (size_t)(b * 49) * 392 + h * 98;
  float2 offr[7];
#pragma unroll
  for (int i = 0; i < 7; ++i) {
    int nl = wv + 4 * i;
    if (nl < rcnt && lane < 49) {
      __half2 o2 =
          *(const __half2*)(offp + (size_t)(bn0 + nl) * 392 + lane * 2);
      offr[i] = __half22float2(o2);
    } else {
      offr[i] = make_float2(0.f, 0.f);
    }
  }

  // ---- P1 stage (pure copies) + full scr zero (once) ----
  {
    short8 zz = {0, 0, 0, 0, 0, 0, 0, 0};
    {
      int r = tid >> 2, c4 = tid & 3;
      short8 pk = zz;
      if (r < 49)
        pk = *(const short8*)(qkv_bf + (size_t)(b * 49 + r) * 384 + 128 +
                              h * 32 + c4 * 8);
      *(short8*)&kbs[r * 40 + c4 * 8] = pk;
    }
    if (tid < 128) {
      int r = tid >> 2, c4 = tid & 3;
      short8 pk = zz;
      if (r < rcnt)
        pk = *(const short8*)(qkv_bf + (size_t)(b * 49 + bn0 + r) * 384 +
                              h * 32 + c4 * 8);
      *(short8*)&qbs[r * 40 + c4 * 8] = pk;
    }
    const short* vbase = qkv_bf + (size_t)(b * 49) * 384 + 256 + h * 32;
#pragma unroll
    for (int it = 0; it < 7; ++it) {
      int i = tid + it * 256;
      if (i < 1568) {
        int n = i >> 5;
        int d = i & 31;
        vbT[d * 72 + n] = vbase[(size_t)n * 384 + d];
      }
    }
    for (int i = tid; i < 480; i += 256) {  // zero vbT cols 49..63, all d
      int d = i / 15;
      int j = i - d * 15;
      vbT[d * 72 + 49 + j] = 0;
    }
    if (tid < 16) S0h[25 * 52 + tid] = __float2half(0.f);
    // zero this wave's FULL scr (50 rows x 64 = 400 chunks of 8)
    for (int c = lane; c < 400; c += 64) *(short8*)&scr[c * 8] = zz;
  }
  __syncthreads();  // B1

  // ---- P2: S0h[n][m] = k_m . q_n via mfma(A=k, B=q); fp16 b64 writes ----
  {
    const int mt = wv;
    short8 af = *(const short8*)&kbs[(mt * 16 + lr) * 40 + lg * 8];
    floatx4 z = {0.f, 0.f, 0.f, 0.f};
#pragma unroll
    for (int nt = 0; nt < 2; ++nt) {
      short8 bf = *(const short8*)&qbs[(nt * 16 + lr) * 40 + lg * 8];
      floatx4 c = __builtin_amdgcn_mfma_f32_16x16x32_bf16(af, bf, z, 0, 0, 0);
      int n = nt * 16 + lr;
      int mbase = mt * 16 + lg * 4;
      if (n < 26 && mbase < 52) {  // both guards required (row pitch 52)
        short4 pk;
        pk.x = (short)__half_as_ushort(__float2half(c[0]));
        pk.y = (short)__half_as_ushort(__float2half(c[1]));
        pk.z = (short)__half_as_ushort(__float2half(c[2]));
        pk.w = (short)__half_as_ushort(__float2half(c[3]));
        *(short4*)&S0h[n * 52 + mbase] = pk;
      }
    }
  }
  __syncthreads();  // B2 (q/k region dead; A2b region writable per-wave)

  // ---- P3: per-wave row loop -- scores + plain scatter + MFMA reduce ----
  {
    short8 bones;
#pragma unroll
    for (int u = 0; u < 8; ++u) bones[u] = (lr == 0) ? (short)0x3F80 : (short)0;
    const int lchunk = lane >> 3;   // scatter column chunk
    const int lsub = lane & 7;

#pragma unroll
    for (int i = 0; i < 7; ++i) {
      const int nl = wv + 4 * i;
      if (nl >= rcnt) break;
      int so0 = 0, so1 = 0, so2 = 0, so3 = 0;
      // scatter: plain bf16 stores, per-lane distinct cells (scr pre-zeroed)
      if (lane < 49) {
        const int gn = bn0 + nl;
        const int iy = (int)((unsigned)gn / 7u);
        const int ix = gn - iy * 7;
        float py = fminf(fmaxf((float)(iy + ky - 3) + offr[i].x, 0.f), 6.f);
        float px = fminf(fmaxf((float)(ix + kx - 3) + offr[i].y, 0.f), 6.f);
        float y0f = floorf(py), x0f = floorf(px);
        float wy = py - y0f, wx = px - x0f;
        int y0 = (int)y0f, x0 = (int)x0f;
        int c00 = y0 * 7 + x0;
        int sbase = nl * 52 + c00;
        float s00 = __half2float(S0h[sbase]);
        float s01 = __half2float(S0h[sbase + 1]);
        float s10 = __half2float(S0h[sbase + 7]);
        float s11 = __half2float(S0h[sbase + 8]);
        float w00 = (1.f - wy) * (1.f - wx);
        float w01 = (1.f - wy) * wx;
        float w10 = wy * (1.f - wx);
        float w11 = wy * wx;
        float s = w00 * s00 + w01 * s01 + w10 * s10 + w11 * s11 + bias_r;
        float pe = __expf(s);
        // duplicate cells (weight==0 exactly) -> single trash row 49
        bool xc = (x0 == 6), yc = (y0 == 6);
        int c01 = xc ? 49 : c00 + 1;
        int c10 = yc ? 49 : c00 + 7;
        int c11 = (xc || yc) ? 49 : c00 + 8;
        so0 = c00 * 64 + ((lchunk ^ (c00 & 7)) * 8) + lsub;
        so1 = c01 * 64 + ((lchunk ^ (c01 & 7)) * 8) + lsub;
        so2 = c10 * 64 + ((lchunk ^ (c10 & 7)) * 8) + lsub;
        so3 = c11 * 64 + ((lchunk ^ (c11 & 7)) * 8) + lsub;
        scr[so0] = f2bf(pe * w00);
        scr[so1] = f2bf(pe * w01);
        scr[so2] = f2bf(pe * w10);
        scr[so3] = f2bf(pe * w11);
      }
      // wave-local handoff: in-order DS pipe; drain + pin schedule
      asm volatile("s_waitcnt lgkmcnt(0)" ::: "memory");
      __builtin_amdgcn_sched_barrier(0);
      // reduce: A2row[m] = sum over 64 cols via ones-B MFMA
#pragma unroll
      for (int tile = 0; tile < 4; ++tile) {
        floatx4 cacc = {0.f, 0.f, 0.f, 0.f};
#pragma unroll
        for (int ks = 0; ks < 2; ++ks) {
          int row = tile * 16 + lr;
          int chunk = ks * 4 + lg;
          short8 af =
              *(const short8*)&scr[row * 64 + ((chunk ^ (row & 7)) * 8)];
          cacc = __builtin_amdgcn_mfma_f32_16x16x32_bf16(af, bones, cacc,
                                                         0, 0, 0);
        }
        if ((lane & 15) == 0) {
          int mb = tile * 16 + (lane >> 4) * 4;
#pragma unroll
          for (int reg = 0; reg < 4; ++reg) {
            int m = mb + reg;
            A2b[nl * 72 + m] = (m <= 48) ? f2bf(cacc[reg]) : (short)0;
          }
        }
      }
      __builtin_amdgcn_sched_barrier(0);  // reduce reads before re-zero
      // re-zero own 4 slots (plain stores; ordered before next scatter by
      // may-alias store ordering + in-order DS pipe)
      if (lane < 49) {
        scr[so0] = 0;
        scr[so1] = 0;
        scr[so2] = 0;
        scr[so3] = 0;
      }
    }
  }
  __syncthreads();  // B3

  // ---- P5: out (bf16, unnormalized) + rowsum via MFMA ----
  {
    const int nt = wv & 1;
    const int dt = wv >> 1;
    floatx4 acc = {0.f, 0.f, 0.f, 0.f};
    floatx4 accS = {0.f, 0.f, 0.f, 0.f};
    short8 bones;
#pragma unroll
    for (int u = 0; u < 8; ++u) bones[u] = (lr == 0) ? (short)0x3F80 : (short)0;
#pragma unroll
    for (int ks = 0; ks < 2; ++ks) {
      short8 af = *(const short8*)&A2b[(nt * 16 + lr) * 72 + ks * 32 + lg * 8];
      short8 bf = *(const short8*)&vbT[(dt * 16 + lr) * 72 + ks * 32 + lg * 8];
      acc = __builtin_amdgcn_mfma_f32_16x16x32_bf16(af, bf, acc, 0, 0, 0);
      if (dt == 0)
        accS = __builtin_amdgcn_mfma_f32_16x16x32_bf16(af, bones, accS, 0, 0, 0);
    }
    const int d = dt * 16 + lr;
#pragma unroll
    for (int reg = 0; reg < 4; ++reg) {
      int n = nt * 16 + lg * 4 + reg;
      if (n < rcnt) {
        int grow = b * 49 + bn0 + n;
        attn_bf[(size_t)grow * 128 + h * 32 + d] = f2bf(acc[reg]);
        if (dt == 0 && lr == 0) rs_buf[(size_t)grow * 4 + h] = accS[reg];
      }
    }
  }
}

// ---------------------------------------------------------------------------
// Proj GEMM: out = diag(1/rs per head) * attn_bf @ w_proj^T + b_proj
// (A input bf16; normalization folded into A-staging.)
// ---------------------------------------------------------------------------
__global__ __launch_bounds__(256) void dwa_proj(
    const short* __restrict__ A, const float* __restrict__ W0,
    const float* __restrict__ bias0, float* __restrict__ out0,
    const float* __restrict__ rs) {
  __shared__ short Abs[64][128];
  __shared__ short Bbs[64][128];
  const int tid = threadIdx.x;
  const int m0 = blockIdx.x * 64;
  const int n0 = blockIdx.y * 64;

#pragma unroll
  for (int p = 0; p < 4; ++p) {
    int c = tid + p * 256;
    int row = c >> 4;
    int slot = c & 15;
    short8 v = *(const short8*)(A + (size_t)(m0 + row) * 128 + slot * 8);
    float irs = 1.0f / rs[(size_t)(m0 + row) * 4 + (slot >> 2)];
    short8 pk;
#pragma unroll
    for (int u = 0; u < 8; ++u) pk[u] = f2bf(bf2f(v[u]) * irs);
    *(short8*)&Abs[row][(slot ^ (row & 7)) * 8] = pk;
  }
#pragma unroll
  for (int p = 0; p < 4; ++p) {
    int c = tid + p * 256;
    int row = c >> 4;
    int slot = c & 15;
    const float* src = W0 + (size_t)(n0 + row) * 128 + slot * 8;
    float4 f0 = *(const float4*)(src);
    float4 f1 = *(const float4*)(src + 4);
    short8 pk;
    pk[0] = f2bf(f0.x); pk[1] = f2bf(f0.y); pk[2] = f2bf(f0.z); pk[3] = f2bf(f0.w);
    pk[4] = f2bf(f1.x); pk[5] = f2bf(f1.y); pk[6] = f2bf(f1.z); pk[7] = f2bf(f1.w);
    *(short8*)&Bbs[row][(slot ^ (row & 7)) * 8] = pk;
  }
  __syncthreads();

  const int lane = tid & 63;
  const int wv = tid >> 6;
  const int wrow = (wv >> 1) * 32;
  const int wcol = (wv & 1) * 32;
  const int lr = lane & 15;
  const int lg = lane >> 4;

  floatx4 acc[2][2];
#pragma unroll
  for (int i = 0; i < 2; ++i)
#pragma unroll
    for (int j = 0; j < 2; ++j) acc[i][j] = {0.f, 0.f, 0.f, 0.f};

#pragma unroll
  for (int ks = 0; ks < 4; ++ks) {
    short8 af[2], bf[2];
#pragma unroll
    for (int i = 0; i < 2; ++i) {
      int r = wrow + i * 16 + lr;
      int slot = (ks * 4 + lg) ^ (r & 7);
      af[i] = *(const short8*)&Abs[r][slot * 8];
    }
#pragma unroll
    for (int j = 0; j < 2; ++j) {
      int r = wcol + j * 16 + lr;
      int slot = (ks * 4 + lg) ^ (r & 7);
      bf[j] = *(const short8*)&Bbs[r][slot * 8];
    }
#pragma unroll
    for (int i = 0; i < 2; ++i)
#pragma unroll
      for (int j = 0; j < 2; ++j)
        acc[i][j] = __builtin_amdgcn_mfma_f32_16x16x32_bf16(af[i], bf[j],
                                                            acc[i][j], 0, 0, 0);
  }

#pragma unroll
  for (int i = 0; i < 2; ++i) {
#pragma unroll
    for (int reg = 0; reg < 4; ++reg) {
      int grow = m0 + wrow + i * 16 + lg * 4 + reg;
#pragma unroll
      for (int j = 0; j < 2; ++j) {
        int gcol = n0 + wcol + j * 16 + lr;
        out0[(size_t)grow * 128 + gcol] = acc[i][j][reg] + bias0[gcol];
      }
    }
  }
}

// ---------------------------------------------------------------------------
extern "C" void kernel_launch(void* const* d_in, const int* in_sizes, int n_in,
                              void* d_out, int out_size, void* d_ws,
                              size_t ws_size, hipStream_t stream) {
  const float* x = (const float*)d_in[0];
  const float* w_qkv = (const float*)d_in[1];
  const float* b_qkv = (const float*)d_in[2];
  const float* w_off = (const float*)d_in[3];
  const float* b_off = (const float*)d_in[4];
  const float* rpb = (const float*)d_in[5];
  const float* w_proj = (const float*)d_in[6];
  const float* b_proj = (const float*)d_in[7];
  float* out = (float*)d_out;

  char* ws = (char*)d_ws;
  short* qkv_bf = (short*)ws;                               // 9,633,792 B
  __half* off_h = (__half*)(ws + 9633792);                  // 9,834,496 B
  short* attn_bf = (short*)(ws + 19468288);                 // 3,211,264 B
  float* rs_buf = (float*)(ws + 22679552);                  // 200,704 B

  dwa_gemm0<<<dim3(196, 5), 256, 0, stream>>>(x, w_qkv, w_off, b_qkv, b_off,
                                              qkv_bf, off_h);
  dwa_attn<<<2048, 256, 0, stream>>>(qkv_bf, off_h, rpb, attn_bf, rs_buf);
  dwa_proj<<<dim3(196, 2), 256, 0, stream>>>(attn_bf, w_proj, b_proj, out,
                                             rs_buf);
}